// Round 10
// baseline (794.935 us; speedup 1.0000x reference)
//
#include <hip/hip_runtime.h>
#include <math.h>

// SimpleGSLModel: B=8192, D=768, TOP_K=5
// R10 = R9 with the s_topk staging bug fixed: global_load_lds dest MUST be lane-linear
//       (wave base + lane*16, rule #21/m104). Thread tid stages rows (tid>>3)+32c, slot
//       tid&7, dest As + c*4096 + tid*16 — same swizzled layout as R8's verified reads.
//       Kept from R9: s_topk 64x64 wave tiles (4 waves, 1.5x less LDS traffic);
//       sgemm_f32 8x8/thread 64x128@128thr w/ contiguous b-reads (bitwise-identical chain).

typedef __attribute__((ext_vector_type(8))) short short8v;
typedef __attribute__((ext_vector_type(4))) float f32x4;

__device__ __forceinline__ unsigned short f2bf(float f) {
  unsigned u = __float_as_uint(f);
  u += 0x7fffu + ((u >> 16) & 1u);   // RNE
  return (unsigned short)(u >> 16);
}
__device__ __forceinline__ float bf2f(unsigned short h) {
  return __uint_as_float(((unsigned)h) << 16);
}
__device__ __forceinline__ float gelu_f(float x) {
  return 0.5f * x * (1.f + erff(x * 0.7071067811865475f));
}
__device__ __forceinline__ void gload16(const void* g, void* l) {
  __builtin_amdgcn_global_load_lds(
      (const __attribute__((address_space(1))) unsigned int*)g,
      (__attribute__((address_space(3))) unsigned int*)l, 16, 0, 0);
}

// sorted-descending insert, static indexing, depth N
template <int N>
__device__ __forceinline__ void insN(float v, int j, float (&lv)[N], int (&li)[N]) {
#pragma unroll
  for (int p = N - 1; p >= 1; --p) {
    bool shiftv = v > lv[p - 1];
    bool here = (v > lv[p]) && !shiftv;
    float nv = shiftv ? lv[p - 1] : (here ? v : lv[p]);
    int ni = shiftv ? li[p - 1] : (here ? j : li[p]);
    lv[p] = nv; li[p] = ni;
  }
  if (v > lv[0]) { lv[0] = v; li[0] = j; }
}

__global__ __launch_bounds__(256) void cvt_bf16(const float* __restrict__ in,
                                                unsigned short* __restrict__ out, int n4) {
  int t = blockIdx.x * 256 + threadIdx.x;
  if (t >= n4) return;
  float4 f = ((const float4*)in)[t];
  ushort4 r;
  r.x = f2bf(f.x); r.y = f2bf(f.y); r.z = f2bf(f.z); r.w = f2bf(f.w);
  ((ushort4*)out)[t] = r;
}

// f32 [rows][K] -> bf16 hi/lo interleaved [rows][2K]
__global__ __launch_bounds__(256) void split2(const float* __restrict__ in,
                                              unsigned short* __restrict__ out,
                                              int K, int n4) {
  int t = blockIdx.x * 256 + threadIdx.x;
  if (t >= n4) return;
  int kq = K >> 2;
  int row = t / kq, c4 = t - row * kq;
  float4 f = ((const float4*)in)[t];
  ushort4 h, l;
  float x;
  x = f.x; h.x = f2bf(x); l.x = f2bf(x - bf2f(h.x));
  x = f.y; h.y = f2bf(x); l.y = f2bf(x - bf2f(h.y));
  x = f.z; h.z = f2bf(x); l.z = f2bf(x - bf2f(h.z));
  x = f.w; h.w = f2bf(x); l.w = f2bf(x - bf2f(h.w));
  *(ushort4*)(out + (size_t)row * 2 * K + c4 * 4) = h;
  *(ushort4*)(out + (size_t)row * 2 * K + K + c4 * 4) = l;
}

// W [K x N] f32 -> transposed hi/lo interleaved bf16 [N][2K]
__global__ __launch_bounds__(256) void split_wt2(const float* __restrict__ W,
                                                 unsigned short* __restrict__ t2,
                                                 int K, int N) {
  __shared__ float tile[32][33];
  int kb = blockIdx.x * 32, nb = blockIdx.y * 32;
  int tx = threadIdx.x & 31, ty = threadIdx.x >> 5;
#pragma unroll
  for (int p = 0; p < 4; ++p)
    tile[ty + p * 8][tx] = W[(size_t)(kb + ty + p * 8) * N + nb + tx];
  __syncthreads();
#pragma unroll
  for (int p = 0; p < 4; ++p) {
    int n = ty + p * 8;
    float x = tile[tx][n];
    unsigned short h = f2bf(x);
    unsigned short l = f2bf(x - bf2f(h));
    t2[(size_t)(nb + n) * (2 * K) + kb + tx] = h;
    t2[(size_t)(nb + n) * (2 * K) + K + kb + tx] = l;
  }
}

// -------- fp32 SGEMM for G. 64x128 tile, 128 thr, 8x8/thread, reg-staged dbuf.
// b-cols per thread: {tc*4..+3} u {64+tc*4..+3} (contiguous reads, conflict-free).
// Per-element fmaf chain (k ascending, single acc) -> bitwise-stable output. --------
__global__ __launch_bounds__(128) void sgemm_f32(const float* __restrict__ A,
                                                 const float* __restrict__ Bm,
                                                 float* __restrict__ C,
                                                 unsigned short* __restrict__ Cbf,
                                                 int N, int K) {
  __shared__ float As[2][16][68];
  __shared__ float Bs[2][16][132];
  const int r0 = blockIdx.x * 64, c0 = blockIdx.y * 128;
  const int tid = threadIdx.x;
  const int tr = tid >> 4, tc = tid & 15;
  const int lrow = tid >> 1, lko = (tid & 1) * 8;
  const int kk = tid >> 5, nq = tid & 31;
  float acc[8][8];
#pragma unroll
  for (int i = 0; i < 8; ++i)
#pragma unroll
    for (int j = 0; j < 8; ++j) acc[i][j] = 0.f;

  const int nk = K >> 4;
  float4 aR0, aR1, bR[4];
  aR0 = *(const float4*)(A + (size_t)(r0 + lrow) * K + lko);
  aR1 = *(const float4*)(A + (size_t)(r0 + lrow) * K + lko + 4);
#pragma unroll
  for (int u = 0; u < 4; ++u)
    bR[u] = *(const float4*)(Bm + (size_t)(kk + 4 * u) * N + c0 + nq * 4);
  As[0][lko + 0][lrow] = aR0.x; As[0][lko + 1][lrow] = aR0.y;
  As[0][lko + 2][lrow] = aR0.z; As[0][lko + 3][lrow] = aR0.w;
  As[0][lko + 4][lrow] = aR1.x; As[0][lko + 5][lrow] = aR1.y;
  As[0][lko + 6][lrow] = aR1.z; As[0][lko + 7][lrow] = aR1.w;
#pragma unroll
  for (int u = 0; u < 4; ++u) *(float4*)&Bs[0][kk + 4 * u][nq * 4] = bR[u];
  __syncthreads();

  int cur = 0;
  for (int t = 0; t < nk; ++t) {
    if (t < nk - 1) {
      int kn = (t + 1) * 16;
      aR0 = *(const float4*)(A + (size_t)(r0 + lrow) * K + kn + lko);
      aR1 = *(const float4*)(A + (size_t)(r0 + lrow) * K + kn + lko + 4);
#pragma unroll
      for (int u = 0; u < 4; ++u)
        bR[u] = *(const float4*)(Bm + (size_t)(kn + kk + 4 * u) * N + c0 + nq * 4);
    }
#pragma unroll
    for (int k = 0; k < 16; ++k) {
      float a[8], b[8];
      *(float4*)&a[0] = *(const float4*)&As[cur][k][tr * 8];
      *(float4*)&a[4] = *(const float4*)&As[cur][k][tr * 8 + 4];
      *(float4*)&b[0] = *(const float4*)&Bs[cur][k][tc * 4];
      *(float4*)&b[4] = *(const float4*)&Bs[cur][k][64 + tc * 4];
#pragma unroll
      for (int i = 0; i < 8; ++i)
#pragma unroll
        for (int j = 0; j < 8; ++j) acc[i][j] = fmaf(a[i], b[j], acc[i][j]);
    }
    if (t < nk - 1) {
      int nxt = cur ^ 1;
      As[nxt][lko + 0][lrow] = aR0.x; As[nxt][lko + 1][lrow] = aR0.y;
      As[nxt][lko + 2][lrow] = aR0.z; As[nxt][lko + 3][lrow] = aR0.w;
      As[nxt][lko + 4][lrow] = aR1.x; As[nxt][lko + 5][lrow] = aR1.y;
      As[nxt][lko + 6][lrow] = aR1.z; As[nxt][lko + 7][lrow] = aR1.w;
#pragma unroll
      for (int u = 0; u < 4; ++u) *(float4*)&Bs[nxt][kk + 4 * u][nq * 4] = bR[u];
    }
    __syncthreads();
    cur ^= 1;
  }
#pragma unroll
  for (int i = 0; i < 8; ++i) {
    int r = r0 + tr * 8 + i;
#pragma unroll
    for (int jq = 0; jq < 2; ++jq) {
      int cb = c0 + jq * 64 + tc * 4;
      *(float4*)(C + (size_t)r * N + cb) = *(float4*)&acc[i][jq * 4];
      ushort4 hb;
      hb.x = f2bf(acc[i][jq * 4 + 0]); hb.y = f2bf(acc[i][jq * 4 + 1]);
      hb.z = f2bf(acc[i][jq * 4 + 2]); hb.w = f2bf(acc[i][jq * 4 + 3]);
      *(ushort4*)(Cbf + (size_t)r * N + cb) = hb;
    }
  }
}

// ---------- bf16 MFMA GEMM, 128x128 tile, swizzled staging, 2-phase dbuf (R8) ----------
// EPI: 0 = raw f32 -> C ; 1 = gelu(x+bias) f32 -> C ; 2 = gelu(x+bias) hi/lo planes -> C2
template <int EPI>
__global__ __launch_bounds__(256) void gemm_bt(const unsigned short* __restrict__ A,
                                               const unsigned short* __restrict__ Bt,
                                               const float* __restrict__ bias,
                                               float* __restrict__ C,
                                               unsigned short* __restrict__ C2,
                                               int N, int K) {
  __shared__ __align__(16) unsigned short As[2 * 128 * 64];
  __shared__ __align__(16) unsigned short Bs[2 * 128 * 64];
  const int r0 = blockIdx.x * 128, c0 = blockIdx.y * 128;
  const int tid = threadIdx.x, lane = tid & 63, w = tid >> 6;
  const int wr = w >> 1, wc = w & 1;
  f32x4 acc[4][4];
  const f32x4 z4 = {0.f, 0.f, 0.f, 0.f};
#pragma unroll
  for (int i = 0; i < 4; ++i)
#pragma unroll
    for (int j = 0; j < 4; ++j) acc[i][j] = z4;

  const int srow = w * 32 + (lane >> 3);
  const int ksl = (lane & 7) ^ (lane >> 3);
  const unsigned short* aSrc = A + (size_t)(r0 + srow) * K + ksl * 8;
  const unsigned short* bSrc = Bt + (size_t)(c0 + srow) * K + ksl * 8;
  const int rsw = (lane & 7);
  const int nk = K >> 6;

#pragma unroll
  for (int t4 = 0; t4 < 4; ++t4) {
    gload16(aSrc + (size_t)t4 * 8 * K, (char*)As + (w * 32 + t4 * 8) * 128);
    gload16(bSrc + (size_t)t4 * 8 * K, (char*)Bs + (w * 32 + t4 * 8) * 128);
  }
  __syncthreads();

  int cur = 0;
  for (int kt = 0; kt < nk; ++kt) {
    if (kt < nk - 1) {
      const int kn = (kt + 1) * 64;
      const int off = (cur ^ 1) * 16384;
#pragma unroll
      for (int t4 = 0; t4 < 4; ++t4) {
        gload16(aSrc + kn + (size_t)t4 * 8 * K, (char*)As + off + (w * 32 + t4 * 8) * 128);
        gload16(bSrc + kn + (size_t)t4 * 8 * K, (char*)Bs + off + (w * 32 + t4 * 8) * 128);
      }
    }
    const int cbase = cur * 16384;
#pragma unroll
    for (int ks = 0; ks < 2; ++ks) {
      short8v af[4], bf[4];
      const int slot = (((ks * 4 + (lane >> 4)) ^ rsw) << 4) + cbase;
#pragma unroll
      for (int f = 0; f < 4; ++f) {
        af[f] = *(const short8v*)((const char*)As + (wr * 64 + f * 16 + (lane & 15)) * 128 + slot);
        bf[f] = *(const short8v*)((const char*)Bs + (wc * 64 + f * 16 + (lane & 15)) * 128 + slot);
      }
#pragma unroll
      for (int fi = 0; fi < 4; ++fi)
#pragma unroll
        for (int fj = 0; fj < 4; ++fj)
          acc[fi][fj] = __builtin_amdgcn_mfma_f32_16x16x32_bf16(af[fi], bf[fj], acc[fi][fj], 0, 0, 0);
    }
    __syncthreads();
    cur ^= 1;
  }
#pragma unroll
  for (int fi = 0; fi < 4; ++fi)
#pragma unroll
    for (int fj = 0; fj < 4; ++fj) {
      int col = c0 + wc * 64 + fj * 16 + (lane & 15);
      int rowb = r0 + wr * 64 + fi * 16 + (lane >> 4) * 4;
#pragma unroll
      for (int r = 0; r < 4; ++r) {
        float x = acc[fi][fj][r];
        if constexpr (EPI == 0) {
          C[(size_t)(rowb + r) * N + col] = x;
        } else if constexpr (EPI == 1) {
          C[(size_t)(rowb + r) * N + col] = gelu_f(x + bias[col]);
        } else {
          float y = gelu_f(x + bias[col]);
          unsigned short h = f2bf(y);
          unsigned short l = f2bf(y - bf2f(h));
          C2[(size_t)(rowb + r) * 2 * N + col] = h;
          C2[(size_t)(rowb + r) * 2 * N + N + col] = l;
        }
      }
    }
}

// ---------- fused S^T tiles + lane-local top-5; 64x64 wave tiles (4 waves 2x2), dbuf ----
// Staging (rule #21 compliant): thread tid stages rows (tid>>3)+32c, slot tid&7,
// dest = buffer + c*4096 + tid*16 (wave base + lane*16). Swizzle: ksl = (tid&7)^((tid>>3)&7),
// invariant under +32c since 32c = 0 mod 8 -> identical layout to R8's verified reads.
// XCD panel map: p=bid&7 (XCD), q=bid>>3; ib=p*8+(q&7); chunk=q>>3.
__global__ __launch_bounds__(256, 2) void s_topk(const unsigned short* __restrict__ Gh,
                                                 const unsigned short* __restrict__ Xh,
                                                 float* __restrict__ pv, int* __restrict__ pix) {
  __shared__ __align__(16) unsigned short As[2 * 128 * 64];   // j-tile dbuf 32 KB
  __shared__ __align__(16) unsigned short Bs[2 * 128 * 64];   // i-tile dbuf 32 KB
  const int bid = blockIdx.x;
  const int p = bid & 7, q = bid >> 3;
  const int r0 = (p * 8 + (q & 7)) * 128;
  const int chunk = q >> 3;
  const int tid = threadIdx.x, lane = tid & 63, w = tid >> 6;   // w in 0..3
  const int wr = w >> 1, wc = w & 1;
  float lv[4][5]; int li[4][5];
#pragma unroll
  for (int f = 0; f < 4; ++f)
#pragma unroll
    for (int q2 = 0; q2 < 5; ++q2) { lv[f][q2] = -1e30f; li[f][q2] = 0; }

  const int srow8 = tid >> 3, sslot = tid & 7;
  const int ksl = sslot ^ (srow8 & 7);
  const unsigned short* bSrcB = Gh + (size_t)(r0 + srow8) * 768 + ksl * 8;  // i rows, fixed
  char* aDst = (char*)As + tid * 16;
  char* bDst = (char*)Bs + tid * 16;
  const int rsw = lane & 7;

  // prologue: jt=0, k0=0 -> buf0
  {
    const unsigned short* aSrcB = Xh + (size_t)(chunk * 1024 + srow8) * 768 + ksl * 8;
#pragma unroll
    for (int c = 0; c < 4; ++c) {
      gload16(aSrcB + (size_t)(32 * c) * 768, aDst + c * 4096);
      gload16(bSrcB + (size_t)(32 * c) * 768, bDst + c * 4096);
    }
  }
  __syncthreads();

  int cur = 0;
  for (int jt = 0; jt < 8; ++jt) {
    const int j0 = chunk * 1024 + jt * 128;
    const unsigned short* aSrcB = Xh + (size_t)(j0 + srow8) * 768 + ksl * 8;
    f32x4 acc[4][4];   // [jfrag][ifrag]
    const f32x4 z4 = {0.f, 0.f, 0.f, 0.f};
#pragma unroll
    for (int i = 0; i < 4; ++i)
#pragma unroll
      for (int j = 0; j < 4; ++j) acc[i][j] = z4;

    for (int t = 0; t < 12; ++t) {
      const int off = (cur ^ 1) * 16384;
      if (t < 11) {
        const int kn = (t + 1) * 64;
#pragma unroll
        for (int c = 0; c < 4; ++c) {
          gload16(aSrcB + kn + (size_t)(32 * c) * 768, aDst + off + c * 4096);
          gload16(bSrcB + kn + (size_t)(32 * c) * 768, bDst + off + c * 4096);
        }
      } else if (jt < 7) {
        // prefetch next jt's k0=0 tile; latency hides under the scan below
        const unsigned short* aN = aSrcB + (size_t)128 * 768;
#pragma unroll
        for (int c = 0; c < 4; ++c) {
          gload16(aN + (size_t)(32 * c) * 768, aDst + off + c * 4096);
          gload16(bSrcB + (size_t)(32 * c) * 768, bDst + off + c * 4096);
        }
      }
      const int cbase = cur * 16384;
#pragma unroll
      for (int ks = 0; ks < 2; ++ks) {
        short8v aj[4], bi[4];
        const int slot = (((ks * 4 + (lane >> 4)) ^ rsw) << 4) + cbase;
#pragma unroll
        for (int f = 0; f < 4; ++f) {
          aj[f] = *(const short8v*)((const char*)As + (wr * 64 + f * 16 + (lane & 15)) * 128 + slot);
          bi[f] = *(const short8v*)((const char*)Bs + (wc * 64 + f * 16 + (lane & 15)) * 128 + slot);
        }
#pragma unroll
        for (int fi = 0; fi < 4; ++fi)
#pragma unroll
          for (int fj = 0; fj < 4; ++fj)
            acc[fi][fj] = __builtin_amdgcn_mfma_f32_16x16x32_bf16(aj[fi], bi[fj], acc[fi][fj], 0, 0, 0);
      }
      __syncthreads();
      cur ^= 1;
    }
    // in-register scan: lane holds 16 j-values for each of 4 i's
    const int jb = j0 + wr * 64 + (lane >> 4) * 4;
#pragma unroll
    for (int fi = 0; fi < 4; ++fi)
#pragma unroll
      for (int r = 0; r < 4; ++r) {
        const int jj = jb + fi * 16 + r;
#pragma unroll
        for (int fj = 0; fj < 4; ++fj) {
          float v = acc[fi][fj][r];
          if (v > lv[fj][4]) insN<5>(v, jj, lv[fj], li[fj]);
        }
      }
  }
  // write per-(i, chunk, slot) top-5; slot = wr*4 + lane-group (same partition as R8)
  const int slotw = wr * 4 + (lane >> 4);
#pragma unroll
  for (int fj = 0; fj < 4; ++fj) {
    const int ib = r0 + wc * 64 + fj * 16 + (lane & 15);
    size_t base = (((size_t)ib * 8 + chunk) * 8 + slotw) * 5;
#pragma unroll
    for (int q2 = 0; q2 < 5; ++q2) { pv[base + q2] = lv[fj][q2]; pix[base + q2] = li[fj][q2]; }
  }
}

// merge 8 chunks x 8 slots x 5 = 320 partial entries per row -> global top-16 candidates
__global__ __launch_bounds__(256) void merge16(const float* __restrict__ pv,
                                               const int* __restrict__ pix,
                                               int* __restrict__ gidx) {
  int row = blockIdx.x * 256 + threadIdx.x;
  float lv[16]; int li[16];
#pragma unroll
  for (int q = 0; q < 16; ++q) { lv[q] = -1e30f; li[q] = 0; }
  for (int ch = 0; ch < 8; ++ch)
#pragma unroll
    for (int sl = 0; sl < 8; ++sl) {
      size_t base = (((size_t)row * 8 + ch) * 8 + sl) * 5;
#pragma unroll
      for (int q = 0; q < 5; ++q) {
        float v = pv[base + q];
        if (v > lv[15]) insN<16>(v, pix[base + q], lv, li);
      }
    }
#pragma unroll
  for (int q = 0; q < 16; ++q) gidx[row * 16 + q] = li[q];
}

// exact f32 re-evaluation of 16 candidates (incl. Ae blend), exact top-5 (ties -> lower index)
__global__ __launch_bounds__(256) void refine5(const float* __restrict__ G,
                                               const float* __restrict__ X,
                                               const float* __restrict__ Ae,
                                               const int* __restrict__ gidx,
                                               const float* __restrict__ ralpha,
                                               int* __restrict__ t5i, float* __restrict__ t5v) {
  int i = blockIdx.x * 4 + (threadIdx.x >> 6);
  int lane = threadIdx.x & 63;
  int c = lane >> 2, s = lane & 3;
  float sa = 1.f / (1.f + expf(-ralpha[0]));
  int j = gidx[i * 16 + c];
  const float* g = G + (size_t)i * 768;
  const float* x = X + (size_t)j * 768;
  float a = 0.f;
#pragma unroll 8
  for (int t = 0; t < 192; ++t) a = fmaf(g[s + 4 * t], x[s + 4 * t], a);
  a += __shfl_xor(a, 1);
  a += __shfl_xor(a, 2);
  float v = sa * Ae[(size_t)i * 8192 + j] + (1.f - sa) * fmaxf(a, 0.f);
  float vs[16]; int js[16];
#pragma unroll
  for (int q = 0; q < 16; ++q) { vs[q] = __shfl(v, q * 4); js[q] = __shfl(j, q * 4); }
  if (lane == 0) {
    unsigned used = 0;
#pragma unroll
    for (int t = 0; t < 5; ++t) {
      float bv = -1e30f; int bj = 0; int bq = 0; bool any = false;
#pragma unroll
      for (int q = 0; q < 16; ++q) {
        bool ok = ((used >> q) & 1u) == 0u;
        bool better = ok && (!any || vs[q] > bv || (vs[q] == bv && js[q] < bj));
        bv = better ? vs[q] : bv; bj = better ? js[q] : bj; bq = better ? q : bq;
        any = any || better;
      }
      used |= (1u << bq);
      t5v[(size_t)i * 5 + t] = bv;
      t5i[(size_t)i * 5 + t] = bj;
    }
  }
}

// -------- symmetrized sparse-A construction (canonical-pair dedup) --------
__global__ void edge_deg(const int* __restrict__ t5i, int* __restrict__ deg) {
  int e = blockIdx.x * 256 + threadIdx.x;
  if (e >= 40960) return;
  int i = e / 5, t = e - i * 5;
  int j = t5i[i * 5 + t];
  if (j == i) return;
  bool rev = false;
#pragma unroll
  for (int u = 0; u < 5; ++u) rev = rev || (t5i[j * 5 + u] == i);
  if (!rev || i < j) { atomicAdd(&deg[i], 1); atomicAdd(&deg[j], 1); }
}

__global__ void scan8k(const int* __restrict__ deg, int* __restrict__ off) {
  __shared__ int sums[256];
  int tid = threadIdx.x;
  int base = tid * 32;
  int s = 0;
  for (int u = 0; u < 32; ++u) s += deg[base + u];
  sums[tid] = s;
  __syncthreads();
  for (int d = 1; d < 256; d <<= 1) {
    int v = (tid >= d) ? sums[tid - d] : 0;
    __syncthreads();
    sums[tid] += v;
    __syncthreads();
  }
  int run = tid ? sums[tid - 1] : 0;
  for (int u = 0; u < 32; ++u) { off[base + u] = run; run += deg[base + u]; }
  if (tid == 255) off[8192] = run;
}

__global__ __launch_bounds__(256) void edge_fill(const int* __restrict__ t5i,
                                                 const float* __restrict__ t5v,
                                                 const float* __restrict__ G,
                                                 const float* __restrict__ X,
                                                 const float* __restrict__ Ae,
                                                 const float* __restrict__ ralpha,
                                                 const int* __restrict__ off,
                                                 int* __restrict__ cursor,
                                                 int* __restrict__ ccol, float* __restrict__ cval) {
  int e = blockIdx.x * 4 + (threadIdx.x >> 6);
  if (e >= 40960) return;
  int lane = threadIdx.x & 63;
  int i = e / 5, t = e - i * 5;
  int j = t5i[i * 5 + t];
  if (j == i) return;
  int rev = -1;
#pragma unroll
  for (int u = 0; u < 5; ++u)
    if (t5i[j * 5 + u] == i) rev = u;
  if (!(rev < 0 || i < j)) return;
  float vji;
  if (rev >= 0) {
    vji = t5v[j * 5 + rev];
  } else {
    const float* g = G + (size_t)j * 768;
    const float* x = X + (size_t)i * 768;
    float a = 0.f;
#pragma unroll
    for (int u = 0; u < 12; ++u) a = fmaf(g[lane + 64 * u], x[lane + 64 * u], a);
#pragma unroll
    for (int d = 32; d; d >>= 1) a += __shfl_xor(a, d);
    float sa = 1.f / (1.f + expf(-ralpha[0]));
    vji = sa * Ae[(size_t)j * 8192 + i] + (1.f - sa) * fmaxf(a, 0.f);
  }
  if (lane == 0) {
    float vij = t5v[i * 5 + t];
    int p0 = off[i] + atomicAdd(&cursor[i], 1);
    ccol[p0] = j; cval[p0] = vij;
    int p1 = off[j] + atomicAdd(&cursor[j], 1);
    ccol[p1] = i; cval[p1] = vji;
  }
}

// M = D^-1 * (X[i] + sum val * X[j]) ; one block per row
__global__ __launch_bounds__(256) void gather_gcn(const float* __restrict__ X,
                                                  const int* __restrict__ off,
                                                  const int* __restrict__ ccol,
                                                  const float* __restrict__ cval,
                                                  float* __restrict__ M) {
  __shared__ float red[256];
  __shared__ float sdinv;
  int i = blockIdx.x, tid = threadIdx.x;
  int s0 = off[i], cnt = off[i + 1] - s0;
  float s = 0.f;
  for (int e = tid; e < cnt; e += 256) s += cval[s0 + e];
  red[tid] = s;
  __syncthreads();
  for (int d = 128; d; d >>= 1) {
    if (tid < d) red[tid] += red[tid + d];
    __syncthreads();
  }
  if (tid == 0) sdinv = 1.f / fmaxf(1.f + red[0], 1e-8f);
  __syncthreads();
  float dinv = sdinv;
  const float* xi = X + (size_t)i * 768;
  float a0 = xi[tid], a1 = xi[tid + 256], a2 = xi[tid + 512];
  for (int e = 0; e < cnt; ++e) {
    float v = cval[s0 + e];
    const float* xr = X + (size_t)ccol[s0 + e] * 768;
    a0 = fmaf(v, xr[tid], a0);
    a1 = fmaf(v, xr[tid + 256], a1);
    a2 = fmaf(v, xr[tid + 512], a2);
  }
  float* mi = M + (size_t)i * 768;
  mi[tid] = a0 * dinv; mi[tid + 256] = a1 * dinv; mi[tid + 512] = a2 * dinv;
}

__global__ __launch_bounds__(256) void final_head(const float* __restrict__ h2,
                                                  const float* __restrict__ W3,
                                                  const float* __restrict__ b3,
                                                  float* __restrict__ out) {
  int i = blockIdx.x * 4 + (threadIdx.x >> 6);
  int lane = threadIdx.x & 63;
  const float* r = h2 + (size_t)i * 256;
  float s = r[lane] * W3[lane] + r[lane + 64] * W3[lane + 64] +
            r[lane + 128] * W3[lane + 128] + r[lane + 192] * W3[lane + 192];
#pragma unroll
  for (int d = 32; d; d >>= 1) s += __shfl_xor(s, d);
  if (lane == 0) out[i] = s + b3[0];
}

extern "C" void kernel_launch(void* const* d_in, const int* in_sizes, int n_in,
                              void* d_out, int out_size, void* d_ws, size_t ws_size,
                              hipStream_t stream) {
  const float* X   = (const float*)d_in[0];
  const float* Ae  = (const float*)d_in[1];
  const float* Wg  = (const float*)d_in[2];
  const float* ra  = (const float*)d_in[3];
  const float* Wgc = (const float*)d_in[4];
  const float* bgc = (const float*)d_in[5];
  const float* W1  = (const float*)d_in[6];
  const float* b1  = (const float*)d_in[7];
  const float* W2  = (const float*)d_in[8];
  const float* b2  = (const float*)d_in[9];
  const float* W3  = (const float*)d_in[10];
  const float* b3  = (const float*)d_in[11];
  float* out = (float*)d_out;

  char* w = (char*)d_ws;
  size_t off_ = 0;
  auto take = [&](size_t n) -> void* {
    void* p = w + off_;
    off_ += (n + 255) & ~(size_t)255;
    return p;
  };
  float* G            = (float*)take((size_t)8192 * 768 * 4);          // 25.17 MB
  unsigned short* Xh  = (unsigned short*)take((size_t)8192 * 768 * 2); // 12.58
  unsigned short* Gh  = (unsigned short*)take((size_t)8192 * 768 * 2); // 12.58
  float* pv           = (float*)take((size_t)8192 * 320 * 4);          // 10.49
  int* pix            = (int*)take((size_t)8192 * 320 * 4);            // 10.49
  int* gidx           = (int*)take((size_t)8192 * 16 * 4);
  int* t5i            = (int*)take((size_t)8192 * 5 * 4);
  float* t5v          = (float*)take((size_t)8192 * 5 * 4);
  int* deg            = (int*)take((size_t)8192 * 4);
  int* offr           = (int*)take((size_t)8193 * 4);
  int* cur            = (int*)take((size_t)8192 * 4);
  int* ccol           = (int*)take((size_t)81920 * 4);
  float* cval         = (float*)take((size_t)81920 * 4);
  unsigned short* Wc2 = (unsigned short*)take((size_t)768 * 1536 * 2); // 2.36
  unsigned short* W12 = (unsigned short*)take((size_t)512 * 1536 * 2); // 1.57
  unsigned short* W22 = (unsigned short*)take((size_t)256 * 1024 * 2); // 0.52
  // total ~76 MB

  // region reuse (stream-ordered):
  float* Mf            = (float*)Xh;            // Xh+Gh: Mf -> Hp2
  unsigned short* Hp2  = (unsigned short*)Xh;
  unsigned short* A2   = (unsigned short*)G;    // G (dead after edge_fill): A2 -> h1p2
  unsigned short* h1p2 = (unsigned short*)G;
  float* h2f = (float*)pv;                      // pv (dead after merge16): h2

  // 1. G = X @ Wg — fp32, k-ascending chain (selection-critical); bf16 copy fused
  sgemm_f32<<<dim3(128, 6), 128, 0, stream>>>(X, Wg, G, Gh, 768, 768);
  // 2. bf16 copy of X
  cvt_bf16<<<6144, 256, 0, stream>>>(X, Xh, 1572864);
  // 3. interleaved weight planes for MLP
  split_wt2<<<dim3(24, 24), 256, 0, stream>>>(Wgc, Wc2, 768, 768);
  split_wt2<<<dim3(24, 16), 256, 0, stream>>>(W1, W12, 768, 512);
  split_wt2<<<dim3(16, 8), 256, 0, stream>>>(W2, W22, 512, 256);

  // 4. fused S^T + lane-local top-5 partials (exact blend in refine5)
  s_topk<<<512, 256, 0, stream>>>(Gh, Xh, pv, pix);
  merge16<<<32, 256, 0, stream>>>(pv, pix, gidx);
  refine5<<<2048, 256, 0, stream>>>(G, X, Ae, gidx, ra, t5i, t5v);

  // 5. sparse symmetric A as CSR
  hipMemsetAsync(deg, 0, 8192 * 4, stream);
  hipMemsetAsync(cur, 0, 8192 * 4, stream);
  edge_deg<<<160, 256, 0, stream>>>(t5i, deg);
  scan8k<<<1, 256, 0, stream>>>(deg, offr);
  edge_fill<<<10240, 256, 0, stream>>>(t5i, t5v, G, X, Ae, ra, offr, cur, ccol, cval);

  // 6. M = A_norm @ X
  gather_gcn<<<8192, 256, 0, stream>>>(X, offr, ccol, cval, Mf);

  // 7. H planes = split(gelu(M @ Wgcn + bgc))
  split2<<<6144, 256, 0, stream>>>(Mf, A2, 768, 1572864);
  gemm_bt<2><<<dim3(64, 6), 256, 0, stream>>>(A2, Wc2, bgc, nullptr, Hp2, 768, 1536);

  // 8. h1 planes = split(gelu(H @ W1 + b1))
  gemm_bt<2><<<dim3(64, 4), 256, 0, stream>>>(Hp2, W12, b1, nullptr, h1p2, 512, 1536);

  // 9. h2 = gelu(h1 @ W2 + b2)
  gemm_bt<1><<<dim3(64, 2), 256, 0, stream>>>(h1p2, W22, b2, h2f, nullptr, 256, 1024);

  // 10. out = h2 @ W3 + b3
  final_head<<<2048, 256, 0, stream>>>(h2f, W3, b3, out);

  (void)in_sizes; (void)n_in; (void)out_size; (void)ws_size;
}

// Round 11
// 693.951 us; speedup vs baseline: 1.1455x; 1.1455x over previous
//
#include <hip/hip_runtime.h>
#include <math.h>

// SimpleGSLModel: B=8192, D=768, TOP_K=5
// R11: sgemm_f32 reverted to R8-proven 256-thr 4x8 version (bitwise-identical G, 160us).
//      s_topk rebuilt: 128j x 256i tile, 512 thr = 8 waves of 64x64 (acc[4][4], 0.5 LDS
//      reads/MFMA), LDS 96KB dbuf, grid 256 = exactly 1 block/CU. Same k-chain per (i,j),
//      same slot->j-set partition as R8 -> selection bitwise identical. Staging dest =
//      base + tid*16 (rule #21). Rest R8-verbatim (passed, absmax 3.9e-3).

typedef __attribute__((ext_vector_type(8))) short short8v;
typedef __attribute__((ext_vector_type(4))) float f32x4;

__device__ __forceinline__ unsigned short f2bf(float f) {
  unsigned u = __float_as_uint(f);
  u += 0x7fffu + ((u >> 16) & 1u);   // RNE
  return (unsigned short)(u >> 16);
}
__device__ __forceinline__ float bf2f(unsigned short h) {
  return __uint_as_float(((unsigned)h) << 16);
}
__device__ __forceinline__ float gelu_f(float x) {
  return 0.5f * x * (1.f + erff(x * 0.7071067811865475f));
}
__device__ __forceinline__ void gload16(const void* g, void* l) {
  __builtin_amdgcn_global_load_lds(
      (const __attribute__((address_space(1))) unsigned int*)g,
      (__attribute__((address_space(3))) unsigned int*)l, 16, 0, 0);
}

// sorted-descending insert, static indexing, depth N
template <int N>
__device__ __forceinline__ void insN(float v, int j, float (&lv)[N], int (&li)[N]) {
#pragma unroll
  for (int p = N - 1; p >= 1; --p) {
    bool shiftv = v > lv[p - 1];
    bool here = (v > lv[p]) && !shiftv;
    float nv = shiftv ? lv[p - 1] : (here ? v : lv[p]);
    int ni = shiftv ? li[p - 1] : (here ? j : li[p]);
    lv[p] = nv; li[p] = ni;
  }
  if (v > lv[0]) { lv[0] = v; li[0] = j; }
}

__global__ __launch_bounds__(256) void cvt_bf16(const float* __restrict__ in,
                                                unsigned short* __restrict__ out, int n4) {
  int t = blockIdx.x * 256 + threadIdx.x;
  if (t >= n4) return;
  float4 f = ((const float4*)in)[t];
  ushort4 r;
  r.x = f2bf(f.x); r.y = f2bf(f.y); r.z = f2bf(f.z); r.w = f2bf(f.w);
  ((ushort4*)out)[t] = r;
}

// f32 [rows][K] -> bf16 hi/lo interleaved [rows][2K]
__global__ __launch_bounds__(256) void split2(const float* __restrict__ in,
                                              unsigned short* __restrict__ out,
                                              int K, int n4) {
  int t = blockIdx.x * 256 + threadIdx.x;
  if (t >= n4) return;
  int kq = K >> 2;
  int row = t / kq, c4 = t - row * kq;
  float4 f = ((const float4*)in)[t];
  ushort4 h, l;
  float x;
  x = f.x; h.x = f2bf(x); l.x = f2bf(x - bf2f(h.x));
  x = f.y; h.y = f2bf(x); l.y = f2bf(x - bf2f(h.y));
  x = f.z; h.z = f2bf(x); l.z = f2bf(x - bf2f(h.z));
  x = f.w; h.w = f2bf(x); l.w = f2bf(x - bf2f(h.w));
  *(ushort4*)(out + (size_t)row * 2 * K + c4 * 4) = h;
  *(ushort4*)(out + (size_t)row * 2 * K + K + c4 * 4) = l;
}

// W [K x N] f32 -> transposed hi/lo interleaved bf16 [N][2K]
__global__ __launch_bounds__(256) void split_wt2(const float* __restrict__ W,
                                                 unsigned short* __restrict__ t2,
                                                 int K, int N) {
  __shared__ float tile[32][33];
  int kb = blockIdx.x * 32, nb = blockIdx.y * 32;
  int tx = threadIdx.x & 31, ty = threadIdx.x >> 5;
#pragma unroll
  for (int p = 0; p < 4; ++p)
    tile[ty + p * 8][tx] = W[(size_t)(kb + ty + p * 8) * N + nb + tx];
  __syncthreads();
#pragma unroll
  for (int p = 0; p < 4; ++p) {
    int n = ty + p * 8;
    float x = tile[tx][n];
    unsigned short h = f2bf(x);
    unsigned short l = f2bf(x - bf2f(h));
    t2[(size_t)(nb + n) * (2 * K) + kb + tx] = h;
    t2[(size_t)(nb + n) * (2 * K) + K + kb + tx] = l;
  }
}

// -------- fp32 SGEMM for G (R8-proven). 64x128 tile, 256 thr, 4x8/thread, reg-staged
// dbuf (1 barrier/step). Per-element fmaf chain (k ascending, single acc) -> bitwise-
// stable output. Fused bf16 copy. --------
__global__ __launch_bounds__(256) void sgemm_f32(const float* __restrict__ A,
                                                 const float* __restrict__ Bm,
                                                 float* __restrict__ C,
                                                 unsigned short* __restrict__ Cbf,
                                                 int N, int K) {
  __shared__ float As[2][16][68];
  __shared__ float Bs[2][16][132];
  const int r0 = blockIdx.x * 64, c0 = blockIdx.y * 128;
  const int tid = threadIdx.x;
  const int tr = tid >> 4, tc = tid & 15;
  const int lrow = tid >> 2, lkq = tid & 3;
  const int kk0 = tid >> 5, nq = tid & 31;
  float acc[4][8];
#pragma unroll
  for (int i = 0; i < 4; ++i)
#pragma unroll
    for (int j = 0; j < 8; ++j) acc[i][j] = 0.f;

  const int nk = K >> 4;
  float4 aR = *(const float4*)(A + (size_t)(r0 + lrow) * K + lkq * 4);
  float4 bR0 = *(const float4*)(Bm + (size_t)kk0 * N + c0 + nq * 4);
  float4 bR1 = *(const float4*)(Bm + (size_t)(kk0 + 8) * N + c0 + nq * 4);
  As[0][lkq * 4 + 0][lrow] = aR.x; As[0][lkq * 4 + 1][lrow] = aR.y;
  As[0][lkq * 4 + 2][lrow] = aR.z; As[0][lkq * 4 + 3][lrow] = aR.w;
  *(float4*)&Bs[0][kk0][nq * 4] = bR0;
  *(float4*)&Bs[0][kk0 + 8][nq * 4] = bR1;
  __syncthreads();

  int cur = 0;
  for (int t = 0; t < nk; ++t) {
    if (t < nk - 1) {
      int kn = (t + 1) * 16;
      aR = *(const float4*)(A + (size_t)(r0 + lrow) * K + kn + lkq * 4);
      bR0 = *(const float4*)(Bm + (size_t)(kn + kk0) * N + c0 + nq * 4);
      bR1 = *(const float4*)(Bm + (size_t)(kn + kk0 + 8) * N + c0 + nq * 4);
    }
#pragma unroll
    for (int k = 0; k < 16; ++k) {
      float a[4], b[8];
      *(float4*)&a[0] = *(const float4*)&As[cur][k][tr * 4];
      *(float4*)&b[0] = *(const float4*)&Bs[cur][k][tc * 8];
      *(float4*)&b[4] = *(const float4*)&Bs[cur][k][tc * 8 + 4];
#pragma unroll
      for (int i = 0; i < 4; ++i)
#pragma unroll
        for (int j = 0; j < 8; ++j) acc[i][j] = fmaf(a[i], b[j], acc[i][j]);
    }
    if (t < nk - 1) {
      int nxt = cur ^ 1;
      As[nxt][lkq * 4 + 0][lrow] = aR.x; As[nxt][lkq * 4 + 1][lrow] = aR.y;
      As[nxt][lkq * 4 + 2][lrow] = aR.z; As[nxt][lkq * 4 + 3][lrow] = aR.w;
      *(float4*)&Bs[nxt][kk0][nq * 4] = bR0;
      *(float4*)&Bs[nxt][kk0 + 8][nq * 4] = bR1;
    }
    __syncthreads();
    cur ^= 1;
  }
#pragma unroll
  for (int i = 0; i < 4; ++i) {
    int r = r0 + tr * 4 + i;
#pragma unroll
    for (int jq = 0; jq < 2; ++jq) {
      *(float4*)(C + (size_t)r * N + c0 + tc * 8 + jq * 4) = *(float4*)&acc[i][jq * 4];
      ushort4 hb;
      hb.x = f2bf(acc[i][jq * 4 + 0]); hb.y = f2bf(acc[i][jq * 4 + 1]);
      hb.z = f2bf(acc[i][jq * 4 + 2]); hb.w = f2bf(acc[i][jq * 4 + 3]);
      *(ushort4*)(Cbf + (size_t)r * N + c0 + tc * 8 + jq * 4) = hb;
    }
  }
}

// ---------- bf16 MFMA GEMM, 128x128 tile, swizzled staging, 2-phase dbuf (R8) ----------
// EPI: 0 = raw f32 -> C ; 1 = gelu(x+bias) f32 -> C ; 2 = gelu(x+bias) hi/lo planes -> C2
template <int EPI>
__global__ __launch_bounds__(256) void gemm_bt(const unsigned short* __restrict__ A,
                                               const unsigned short* __restrict__ Bt,
                                               const float* __restrict__ bias,
                                               float* __restrict__ C,
                                               unsigned short* __restrict__ C2,
                                               int N, int K) {
  __shared__ __align__(16) unsigned short As[2 * 128 * 64];
  __shared__ __align__(16) unsigned short Bs[2 * 128 * 64];
  const int r0 = blockIdx.x * 128, c0 = blockIdx.y * 128;
  const int tid = threadIdx.x, lane = tid & 63, w = tid >> 6;
  const int wr = w >> 1, wc = w & 1;
  f32x4 acc[4][4];
  const f32x4 z4 = {0.f, 0.f, 0.f, 0.f};
#pragma unroll
  for (int i = 0; i < 4; ++i)
#pragma unroll
    for (int j = 0; j < 4; ++j) acc[i][j] = z4;

  const int srow = w * 32 + (lane >> 3);
  const int ksl = (lane & 7) ^ (lane >> 3);
  const unsigned short* aSrc = A + (size_t)(r0 + srow) * K + ksl * 8;
  const unsigned short* bSrc = Bt + (size_t)(c0 + srow) * K + ksl * 8;
  const int rsw = (lane & 7);
  const int nk = K >> 6;

#pragma unroll
  for (int t4 = 0; t4 < 4; ++t4) {
    gload16(aSrc + (size_t)t4 * 8 * K, (char*)As + (w * 32 + t4 * 8) * 128);
    gload16(bSrc + (size_t)t4 * 8 * K, (char*)Bs + (w * 32 + t4 * 8) * 128);
  }
  __syncthreads();

  int cur = 0;
  for (int kt = 0; kt < nk; ++kt) {
    if (kt < nk - 1) {
      const int kn = (kt + 1) * 64;
      const int off = (cur ^ 1) * 16384;
#pragma unroll
      for (int t4 = 0; t4 < 4; ++t4) {
        gload16(aSrc + kn + (size_t)t4 * 8 * K, (char*)As + off + (w * 32 + t4 * 8) * 128);
        gload16(bSrc + kn + (size_t)t4 * 8 * K, (char*)Bs + off + (w * 32 + t4 * 8) * 128);
      }
    }
    const int cbase = cur * 16384;
#pragma unroll
    for (int ks = 0; ks < 2; ++ks) {
      short8v af[4], bf[4];
      const int slot = (((ks * 4 + (lane >> 4)) ^ rsw) << 4) + cbase;
#pragma unroll
      for (int f = 0; f < 4; ++f) {
        af[f] = *(const short8v*)((const char*)As + (wr * 64 + f * 16 + (lane & 15)) * 128 + slot);
        bf[f] = *(const short8v*)((const char*)Bs + (wc * 64 + f * 16 + (lane & 15)) * 128 + slot);
      }
#pragma unroll
      for (int fi = 0; fi < 4; ++fi)
#pragma unroll
        for (int fj = 0; fj < 4; ++fj)
          acc[fi][fj] = __builtin_amdgcn_mfma_f32_16x16x32_bf16(af[fi], bf[fj], acc[fi][fj], 0, 0, 0);
    }
    __syncthreads();
    cur ^= 1;
  }
#pragma unroll
  for (int fi = 0; fi < 4; ++fi)
#pragma unroll
    for (int fj = 0; fj < 4; ++fj) {
      int col = c0 + wc * 64 + fj * 16 + (lane & 15);
      int rowb = r0 + wr * 64 + fi * 16 + (lane >> 4) * 4;
#pragma unroll
      for (int r = 0; r < 4; ++r) {
        float x = acc[fi][fj][r];
        if constexpr (EPI == 0) {
          C[(size_t)(rowb + r) * N + col] = x;
        } else if constexpr (EPI == 1) {
          C[(size_t)(rowb + r) * N + col] = gelu_f(x + bias[col]);
        } else {
          float y = gelu_f(x + bias[col]);
          unsigned short h = f2bf(y);
          unsigned short l = f2bf(y - bf2f(h));
          C2[(size_t)(rowb + r) * 2 * N + col] = h;
          C2[(size_t)(rowb + r) * 2 * N + N + col] = l;
        }
      }
    }
}

// ---------- fused S^T + lane-local top-5: 128j x 256i tile, 8 waves of 64x64, dbuf ----
// Grid 256 blocks = 1/CU. Wave w: jhalf = w>>2 (0..1), iquart = w&3 (0..3).
// Staging (rule #21): dest = chunkbase + tid*16; src row = c*64 + (tid>>3), slot tid&7,
// ksl = (tid&7)^((tid>>3)&7) (rows mod 8 invariant under +64c). Same layout as R8 reads.
// Slot partition (jhalf*4 + lanegroup) covers the SAME j-sets as R8 -> selection identical.
// XCD map: p=bid&7 (XCD), q=bid>>3; ib = p*4 + (q&3); chunk = q>>2.
__global__ __launch_bounds__(512, 1) void s_topk(const unsigned short* __restrict__ Gh,
                                                 const unsigned short* __restrict__ Xh,
                                                 float* __restrict__ pv, int* __restrict__ pix) {
  __shared__ __align__(16) unsigned short As[2 * 128 * 64];   // j-tile dbuf 32 KB
  __shared__ __align__(16) unsigned short Bs[2 * 256 * 64];   // i-tile dbuf 64 KB
  const int bid = blockIdx.x;
  const int p = bid & 7, q = bid >> 3;
  const int r0i = (p * 4 + (q & 3)) * 256;
  const int chunk = q >> 2;
  const int tid = threadIdx.x, lane = tid & 63, w = tid >> 6;
  const int jh = w >> 2, iq = w & 3;
  float lv[4][5]; int li[4][5];
#pragma unroll
  for (int f = 0; f < 4; ++f)
#pragma unroll
    for (int q2 = 0; q2 < 5; ++q2) { lv[f][q2] = -1e30f; li[f][q2] = 0; }

  const int srow8 = tid >> 3, sslot = tid & 7;
  const int ksl = sslot ^ (srow8 & 7);
  const unsigned short* bS = Gh + (size_t)(r0i + srow8) * 768 + ksl * 8;   // i rows, fixed
  char* aDst = (char*)As + tid * 16;
  char* bDst = (char*)Bs + tid * 16;
  const int rsw = lane & 7;

  // prologue: jt=0, k0=0 -> buf0
  {
    const unsigned short* aS0 = Xh + (size_t)(chunk * 1024 + srow8) * 768 + ksl * 8;
#pragma unroll
    for (int c = 0; c < 2; ++c) gload16(aS0 + (size_t)(64 * c) * 768, aDst + c * 8192);
#pragma unroll
    for (int c = 0; c < 4; ++c) gload16(bS + (size_t)(64 * c) * 768, bDst + c * 8192);
  }
  __syncthreads();

  int cur = 0;
  for (int jt = 0; jt < 8; ++jt) {
    const int j0 = chunk * 1024 + jt * 128;
    const unsigned short* aS = Xh + (size_t)(j0 + srow8) * 768 + ksl * 8;
    f32x4 acc[4][4];   // [jfrag][ifrag]
    const f32x4 z4 = {0.f, 0.f, 0.f, 0.f};
#pragma unroll
    for (int i = 0; i < 4; ++i)
#pragma unroll
      for (int j = 0; j < 4; ++j) acc[i][j] = z4;

    for (int t = 0; t < 12; ++t) {
      const int offA = (cur ^ 1) * 16384;
      const int offB = (cur ^ 1) * 32768;
      if (t < 11) {
        const int kn = (t + 1) * 64;
#pragma unroll
        for (int c = 0; c < 2; ++c) gload16(aS + kn + (size_t)(64 * c) * 768, aDst + offA + c * 8192);
#pragma unroll
        for (int c = 0; c < 4; ++c) gload16(bS + kn + (size_t)(64 * c) * 768, bDst + offB + c * 8192);
      } else if (jt < 7) {
        // prefetch next jt's k0=0 tile; HBM latency hides under the scan below
        const unsigned short* aN = aS + (size_t)128 * 768;
#pragma unroll
        for (int c = 0; c < 2; ++c) gload16(aN + (size_t)(64 * c) * 768, aDst + offA + c * 8192);
#pragma unroll
        for (int c = 0; c < 4; ++c) gload16(bS + (size_t)(64 * c) * 768, bDst + offB + c * 8192);
      }
      const int cA = cur * 16384, cB = cur * 32768;
#pragma unroll
      for (int ks = 0; ks < 2; ++ks) {
        short8v aj[4], bi[4];
        const int slot = ((ks * 4 + (lane >> 4)) ^ rsw) << 4;
#pragma unroll
        for (int f = 0; f < 4; ++f) {
          aj[f] = *(const short8v*)((const char*)As + (jh * 64 + f * 16 + (lane & 15)) * 128 + slot + cA);
          bi[f] = *(const short8v*)((const char*)Bs + (iq * 64 + f * 16 + (lane & 15)) * 128 + slot + cB);
        }
#pragma unroll
        for (int fi = 0; fi < 4; ++fi)
#pragma unroll
          for (int fj = 0; fj < 4; ++fj)
            acc[fi][fj] = __builtin_amdgcn_mfma_f32_16x16x32_bf16(aj[fi], bi[fj], acc[fi][fj], 0, 0, 0);
      }
      __syncthreads();
      cur ^= 1;
    }
    // in-register scan: lane holds 16 j-values for each of 4 i's
    const int jb = j0 + jh * 64 + (lane >> 4) * 4;
#pragma unroll
    for (int fi = 0; fi < 4; ++fi)
#pragma unroll
      for (int r = 0; r < 4; ++r) {
        const int jj = jb + fi * 16 + r;
#pragma unroll
        for (int fj = 0; fj < 4; ++fj) {
          float v = acc[fi][fj][r];
          if (v > lv[fj][4]) insN<5>(v, jj, lv[fj], li[fj]);
        }
      }
  }
  // write per-(i, chunk, slot) top-5; slot = jh*4 + lane-group (same j-partition as R8)
  const int slotw = jh * 4 + (lane >> 4);
#pragma unroll
  for (int fj = 0; fj < 4; ++fj) {
    const int ib = r0i + iq * 64 + fj * 16 + (lane & 15);
    size_t base = (((size_t)ib * 8 + chunk) * 8 + slotw) * 5;
#pragma unroll
    for (int q2 = 0; q2 < 5; ++q2) { pv[base + q2] = lv[fj][q2]; pix[base + q2] = li[fj][q2]; }
  }
}

// merge 8 chunks x 8 slots x 5 = 320 partial entries per row -> global top-16 candidates
__global__ __launch_bounds__(256) void merge16(const float* __restrict__ pv,
                                               const int* __restrict__ pix,
                                               int* __restrict__ gidx) {
  int row = blockIdx.x * 256 + threadIdx.x;
  float lv[16]; int li[16];
#pragma unroll
  for (int q = 0; q < 16; ++q) { lv[q] = -1e30f; li[q] = 0; }
  for (int ch = 0; ch < 8; ++ch)
#pragma unroll
    for (int sl = 0; sl < 8; ++sl) {
      size_t base = (((size_t)row * 8 + ch) * 8 + sl) * 5;
#pragma unroll
      for (int q = 0; q < 5; ++q) {
        float v = pv[base + q];
        if (v > lv[15]) insN<16>(v, pix[base + q], lv, li);
      }
    }
#pragma unroll
  for (int q = 0; q < 16; ++q) gidx[row * 16 + q] = li[q];
}

// exact f32 re-evaluation of 16 candidates (incl. Ae blend), exact top-5 (ties -> lower index)
__global__ __launch_bounds__(256) void refine5(const float* __restrict__ G,
                                               const float* __restrict__ X,
                                               const float* __restrict__ Ae,
                                               const int* __restrict__ gidx,
                                               const float* __restrict__ ralpha,
                                               int* __restrict__ t5i, float* __restrict__ t5v) {
  int i = blockIdx.x * 4 + (threadIdx.x >> 6);
  int lane = threadIdx.x & 63;
  int c = lane >> 2, s = lane & 3;
  float sa = 1.f / (1.f + expf(-ralpha[0]));
  int j = gidx[i * 16 + c];
  const float* g = G + (size_t)i * 768;
  const float* x = X + (size_t)j * 768;
  float a = 0.f;
#pragma unroll 8
  for (int t = 0; t < 192; ++t) a = fmaf(g[s + 4 * t], x[s + 4 * t], a);
  a += __shfl_xor(a, 1);
  a += __shfl_xor(a, 2);
  float v = sa * Ae[(size_t)i * 8192 + j] + (1.f - sa) * fmaxf(a, 0.f);
  float vs[16]; int js[16];
#pragma unroll
  for (int q = 0; q < 16; ++q) { vs[q] = __shfl(v, q * 4); js[q] = __shfl(j, q * 4); }
  if (lane == 0) {
    unsigned used = 0;
#pragma unroll
    for (int t = 0; t < 5; ++t) {
      float bv = -1e30f; int bj = 0; int bq = 0; bool any = false;
#pragma unroll
      for (int q = 0; q < 16; ++q) {
        bool ok = ((used >> q) & 1u) == 0u;
        bool better = ok && (!any || vs[q] > bv || (vs[q] == bv && js[q] < bj));
        bv = better ? vs[q] : bv; bj = better ? js[q] : bj; bq = better ? q : bq;
        any = any || better;
      }
      used |= (1u << bq);
      t5v[(size_t)i * 5 + t] = bv;
      t5i[(size_t)i * 5 + t] = bj;
    }
  }
}

// -------- symmetrized sparse-A construction (canonical-pair dedup) --------
__global__ void edge_deg(const int* __restrict__ t5i, int* __restrict__ deg) {
  int e = blockIdx.x * 256 + threadIdx.x;
  if (e >= 40960) return;
  int i = e / 5, t = e - i * 5;
  int j = t5i[i * 5 + t];
  if (j == i) return;
  bool rev = false;
#pragma unroll
  for (int u = 0; u < 5; ++u) rev = rev || (t5i[j * 5 + u] == i);
  if (!rev || i < j) { atomicAdd(&deg[i], 1); atomicAdd(&deg[j], 1); }
}

__global__ void scan8k(const int* __restrict__ deg, int* __restrict__ off) {
  __shared__ int sums[256];
  int tid = threadIdx.x;
  int base = tid * 32;
  int s = 0;
  for (int u = 0; u < 32; ++u) s += deg[base + u];
  sums[tid] = s;
  __syncthreads();
  for (int d = 1; d < 256; d <<= 1) {
    int v = (tid >= d) ? sums[tid - d] : 0;
    __syncthreads();
    sums[tid] += v;
    __syncthreads();
  }
  int run = tid ? sums[tid - 1] : 0;
  for (int u = 0; u < 32; ++u) { off[base + u] = run; run += deg[base + u]; }
  if (tid == 255) off[8192] = run;
}

__global__ __launch_bounds__(256) void edge_fill(const int* __restrict__ t5i,
                                                 const float* __restrict__ t5v,
                                                 const float* __restrict__ G,
                                                 const float* __restrict__ X,
                                                 const float* __restrict__ Ae,
                                                 const float* __restrict__ ralpha,
                                                 const int* __restrict__ off,
                                                 int* __restrict__ cursor,
                                                 int* __restrict__ ccol, float* __restrict__ cval) {
  int e = blockIdx.x * 4 + (threadIdx.x >> 6);
  if (e >= 40960) return;
  int lane = threadIdx.x & 63;
  int i = e / 5, t = e - i * 5;
  int j = t5i[i * 5 + t];
  if (j == i) return;
  int rev = -1;
#pragma unroll
  for (int u = 0; u < 5; ++u)
    if (t5i[j * 5 + u] == i) rev = u;
  if (!(rev < 0 || i < j)) return;
  float vji;
  if (rev >= 0) {
    vji = t5v[j * 5 + rev];
  } else {
    const float* g = G + (size_t)j * 768;
    const float* x = X + (size_t)i * 768;
    float a = 0.f;
#pragma unroll
    for (int u = 0; u < 12; ++u) a = fmaf(g[lane + 64 * u], x[lane + 64 * u], a);
#pragma unroll
    for (int d = 32; d; d >>= 1) a += __shfl_xor(a, d);
    float sa = 1.f / (1.f + expf(-ralpha[0]));
    vji = sa * Ae[(size_t)j * 8192 + i] + (1.f - sa) * fmaxf(a, 0.f);
  }
  if (lane == 0) {
    float vij = t5v[i * 5 + t];
    int p0 = off[i] + atomicAdd(&cursor[i], 1);
    ccol[p0] = j; cval[p0] = vij;
    int p1 = off[j] + atomicAdd(&cursor[j], 1);
    ccol[p1] = i; cval[p1] = vji;
  }
}

// M = D^-1 * (X[i] + sum val * X[j]) ; one block per row
__global__ __launch_bounds__(256) void gather_gcn(const float* __restrict__ X,
                                                  const int* __restrict__ off,
                                                  const int* __restrict__ ccol,
                                                  const float* __restrict__ cval,
                                                  float* __restrict__ M) {
  __shared__ float red[256];
  __shared__ float sdinv;
  int i = blockIdx.x, tid = threadIdx.x;
  int s0 = off[i], cnt = off[i + 1] - s0;
  float s = 0.f;
  for (int e = tid; e < cnt; e += 256) s += cval[s0 + e];
  red[tid] = s;
  __syncthreads();
  for (int d = 128; d; d >>= 1) {
    if (tid < d) red[tid] += red[tid + d];
    __syncthreads();
  }
  if (tid == 0) sdinv = 1.f / fmaxf(1.f + red[0], 1e-8f);
  __syncthreads();
  float dinv = sdinv;
  const float* xi = X + (size_t)i * 768;
  float a0 = xi[tid], a1 = xi[tid + 256], a2 = xi[tid + 512];
  for (int e = 0; e < cnt; ++e) {
    float v = cval[s0 + e];
    const float* xr = X + (size_t)ccol[s0 + e] * 768;
    a0 = fmaf(v, xr[tid], a0);
    a1 = fmaf(v, xr[tid + 256], a1);
    a2 = fmaf(v, xr[tid + 512], a2);
  }
  float* mi = M + (size_t)i * 768;
  mi[tid] = a0 * dinv; mi[tid + 256] = a1 * dinv; mi[tid + 512] = a2 * dinv;
}

__global__ __launch_bounds__(256) void final_head(const float* __restrict__ h2,
                                                  const float* __restrict__ W3,
                                                  const float* __restrict__ b3,
                                                  float* __restrict__ out) {
  int i = blockIdx.x * 4 + (threadIdx.x >> 6);
  int lane = threadIdx.x & 63;
  const float* r = h2 + (size_t)i * 256;
  float s = r[lane] * W3[lane] + r[lane + 64] * W3[lane + 64] +
            r[lane + 128] * W3[lane + 128] + r[lane + 192] * W3[lane + 192];
#pragma unroll
  for (int d = 32; d; d >>= 1) s += __shfl_xor(s, d);
  if (lane == 0) out[i] = s + b3[0];
}

extern "C" void kernel_launch(void* const* d_in, const int* in_sizes, int n_in,
                              void* d_out, int out_size, void* d_ws, size_t ws_size,
                              hipStream_t stream) {
  const float* X   = (const float*)d_in[0];
  const float* Ae  = (const float*)d_in[1];
  const float* Wg  = (const float*)d_in[2];
  const float* ra  = (const float*)d_in[3];
  const float* Wgc = (const float*)d_in[4];
  const float* bgc = (const float*)d_in[5];
  const float* W1  = (const float*)d_in[6];
  const float* b1  = (const float*)d_in[7];
  const float* W2  = (const float*)d_in[8];
  const float* b2  = (const float*)d_in[9];
  const float* W3  = (const float*)d_in[10];
  const float* b3  = (const float*)d_in[11];
  float* out = (float*)d_out;

  char* w = (char*)d_ws;
  size_t off_ = 0;
  auto take = [&](size_t n) -> void* {
    void* p = w + off_;
    off_ += (n + 255) & ~(size_t)255;
    return p;
  };
  float* G            = (float*)take((size_t)8192 * 768 * 4);          // 25.17 MB
  unsigned short* Xh  = (unsigned short*)take((size_t)8192 * 768 * 2); // 12.58
  unsigned short* Gh  = (unsigned short*)take((size_t)8192 * 768 * 2); // 12.58
  float* pv           = (float*)take((size_t)8192 * 320 * 4);          // 10.49
  int* pix            = (int*)take((size_t)8192 * 320 * 4);            // 10.49
  int* gidx           = (int*)take((size_t)8192 * 16 * 4);
  int* t5i            = (int*)take((size_t)8192 * 5 * 4);
  float* t5v          = (float*)take((size_t)8192 * 5 * 4);
  int* deg            = (int*)take((size_t)8192 * 4);
  int* offr           = (int*)take((size_t)8193 * 4);
  int* cur            = (int*)take((size_t)8192 * 4);
  int* ccol           = (int*)take((size_t)81920 * 4);
  float* cval         = (float*)take((size_t)81920 * 4);
  unsigned short* Wc2 = (unsigned short*)take((size_t)768 * 1536 * 2); // 2.36
  unsigned short* W12 = (unsigned short*)take((size_t)512 * 1536 * 2); // 1.57
  unsigned short* W22 = (unsigned short*)take((size_t)256 * 1024 * 2); // 0.52
  // total ~76 MB

  // region reuse (stream-ordered):
  float* Mf            = (float*)Xh;            // Xh+Gh: Mf -> Hp2
  unsigned short* Hp2  = (unsigned short*)Xh;
  unsigned short* A2   = (unsigned short*)G;    // G (dead after edge_fill): A2 -> h1p2
  unsigned short* h1p2 = (unsigned short*)G;
  float* h2f = (float*)pv;                      // pv (dead after merge16): h2

  // 1. G = X @ Wg — fp32, k-ascending chain (selection-critical); bf16 copy fused
  sgemm_f32<<<dim3(128, 6), 256, 0, stream>>>(X, Wg, G, Gh, 768, 768);
  // 2. bf16 copy of X
  cvt_bf16<<<6144, 256, 0, stream>>>(X, Xh, 1572864);
  // 3. interleaved weight planes for MLP
  split_wt2<<<dim3(24, 24), 256, 0, stream>>>(Wgc, Wc2, 768, 768);
  split_wt2<<<dim3(24, 16), 256, 0, stream>>>(W1, W12, 768, 512);
  split_wt2<<<dim3(16, 8), 256, 0, stream>>>(W2, W22, 512, 256);

  // 4. fused S^T + lane-local top-5 partials (exact blend in refine5)
  s_topk<<<256, 512, 0, stream>>>(Gh, Xh, pv, pix);
  merge16<<<32, 256, 0, stream>>>(pv, pix, gidx);
  refine5<<<2048, 256, 0, stream>>>(G, X, Ae, gidx, ra, t5i, t5v);

  // 5. sparse symmetric A as CSR
  hipMemsetAsync(deg, 0, 8192 * 4, stream);
  hipMemsetAsync(cur, 0, 8192 * 4, stream);
  edge_deg<<<160, 256, 0, stream>>>(t5i, deg);
  scan8k<<<1, 256, 0, stream>>>(deg, offr);
  edge_fill<<<10240, 256, 0, stream>>>(t5i, t5v, G, X, Ae, ra, offr, cur, ccol, cval);

  // 6. M = A_norm @ X
  gather_gcn<<<8192, 256, 0, stream>>>(X, offr, ccol, cval, Mf);

  // 7. H planes = split(gelu(M @ Wgcn + bgc))
  split2<<<6144, 256, 0, stream>>>(Mf, A2, 768, 1572864);
  gemm_bt<2><<<dim3(64, 6), 256, 0, stream>>>(A2, Wc2, bgc, nullptr, Hp2, 768, 1536);

  // 8. h1 planes = split(gelu(H @ W1 + b1))
  gemm_bt<2><<<dim3(64, 4), 256, 0, stream>>>(Hp2, W12, b1, nullptr, h1p2, 512, 1536);

  // 9. h2 = gelu(h1 @ W2 + b2)
  gemm_bt<1><<<dim3(64, 2), 256, 0, stream>>>(h1p2, W22, b2, h2f, nullptr, 256, 1024);

  // 10. out = h2 @ W3 + b3
  final_head<<<2048, 256, 0, stream>>>(h2f, W3, b3, out);

  (void)in_sizes; (void)n_in; (void)out_size; (void)ws_size;
}

// Round 12
// 647.649 us; speedup vs baseline: 1.2274x; 1.0715x over previous
//
#include <hip/hip_runtime.h>
#include <math.h>

// SimpleGSLModel: B=8192, D=768, TOP_K=5
// R12 = R8 (best passing config, 661us) + one surgical fix:
//   sgemm_f32 b-column remap {tc*8..+7} -> {tc*4..+3} u {64+tc*4..+3}: both LDS b-reads
//   become 256B-contiguous (2-way = free), killing the measured 2e7 bank conflicts.
//   Per-output-element fmaf chain unchanged -> G bitwise identical (selection-critical).
// s_topk reverted to R8-verbatim (R9/R10/R11 redesigns all failed to beat it).

typedef __attribute__((ext_vector_type(8))) short short8v;
typedef __attribute__((ext_vector_type(4))) float f32x4;

__device__ __forceinline__ unsigned short f2bf(float f) {
  unsigned u = __float_as_uint(f);
  u += 0x7fffu + ((u >> 16) & 1u);   // RNE
  return (unsigned short)(u >> 16);
}
__device__ __forceinline__ float bf2f(unsigned short h) {
  return __uint_as_float(((unsigned)h) << 16);
}
__device__ __forceinline__ float gelu_f(float x) {
  return 0.5f * x * (1.f + erff(x * 0.7071067811865475f));
}
__device__ __forceinline__ void gload16(const void* g, void* l) {
  __builtin_amdgcn_global_load_lds(
      (const __attribute__((address_space(1))) unsigned int*)g,
      (__attribute__((address_space(3))) unsigned int*)l, 16, 0, 0);
}

// sorted-descending insert, static indexing, depth N
template <int N>
__device__ __forceinline__ void insN(float v, int j, float (&lv)[N], int (&li)[N]) {
#pragma unroll
  for (int p = N - 1; p >= 1; --p) {
    bool shiftv = v > lv[p - 1];
    bool here = (v > lv[p]) && !shiftv;
    float nv = shiftv ? lv[p - 1] : (here ? v : lv[p]);
    int ni = shiftv ? li[p - 1] : (here ? j : li[p]);
    lv[p] = nv; li[p] = ni;
  }
  if (v > lv[0]) { lv[0] = v; li[0] = j; }
}

__global__ __launch_bounds__(256) void cvt_bf16(const float* __restrict__ in,
                                                unsigned short* __restrict__ out, int n4) {
  int t = blockIdx.x * 256 + threadIdx.x;
  if (t >= n4) return;
  float4 f = ((const float4*)in)[t];
  ushort4 r;
  r.x = f2bf(f.x); r.y = f2bf(f.y); r.z = f2bf(f.z); r.w = f2bf(f.w);
  ((ushort4*)out)[t] = r;
}

// f32 [rows][K] -> bf16 hi/lo interleaved [rows][2K]
__global__ __launch_bounds__(256) void split2(const float* __restrict__ in,
                                              unsigned short* __restrict__ out,
                                              int K, int n4) {
  int t = blockIdx.x * 256 + threadIdx.x;
  if (t >= n4) return;
  int kq = K >> 2;
  int row = t / kq, c4 = t - row * kq;
  float4 f = ((const float4*)in)[t];
  ushort4 h, l;
  float x;
  x = f.x; h.x = f2bf(x); l.x = f2bf(x - bf2f(h.x));
  x = f.y; h.y = f2bf(x); l.y = f2bf(x - bf2f(h.y));
  x = f.z; h.z = f2bf(x); l.z = f2bf(x - bf2f(h.z));
  x = f.w; h.w = f2bf(x); l.w = f2bf(x - bf2f(h.w));
  *(ushort4*)(out + (size_t)row * 2 * K + c4 * 4) = h;
  *(ushort4*)(out + (size_t)row * 2 * K + K + c4 * 4) = l;
}

// W [K x N] f32 -> transposed hi/lo interleaved bf16 [N][2K]
__global__ __launch_bounds__(256) void split_wt2(const float* __restrict__ W,
                                                 unsigned short* __restrict__ t2,
                                                 int K, int N) {
  __shared__ float tile[32][33];
  int kb = blockIdx.x * 32, nb = blockIdx.y * 32;
  int tx = threadIdx.x & 31, ty = threadIdx.x >> 5;
#pragma unroll
  for (int p = 0; p < 4; ++p)
    tile[ty + p * 8][tx] = W[(size_t)(kb + ty + p * 8) * N + nb + tx];
  __syncthreads();
#pragma unroll
  for (int p = 0; p < 4; ++p) {
    int n = ty + p * 8;
    float x = tile[tx][n];
    unsigned short h = f2bf(x);
    unsigned short l = f2bf(x - bf2f(h));
    t2[(size_t)(nb + n) * (2 * K) + kb + tx] = h;
    t2[(size_t)(nb + n) * (2 * K) + K + kb + tx] = l;
  }
}

// -------- fp32 SGEMM for G. 64x128 tile, 256 thr, 4x8/thread, reg-staged dbuf.
// b-cols per thread: {tc*4..+3} u {64+tc*4..+3} -> 256B-contiguous LDS reads (conflict-
// free). Per-element fmaf chain (k ascending, single acc) -> bitwise-stable output.
// Fused bf16 copy. --------
__global__ __launch_bounds__(256) void sgemm_f32(const float* __restrict__ A,
                                                 const float* __restrict__ Bm,
                                                 float* __restrict__ C,
                                                 unsigned short* __restrict__ Cbf,
                                                 int N, int K) {
  __shared__ float As[2][16][68];
  __shared__ float Bs[2][16][132];
  const int r0 = blockIdx.x * 64, c0 = blockIdx.y * 128;
  const int tid = threadIdx.x;
  const int tr = tid >> 4, tc = tid & 15;
  const int lrow = tid >> 2, lkq = tid & 3;
  const int kk0 = tid >> 5, nq = tid & 31;
  float acc[4][8];
#pragma unroll
  for (int i = 0; i < 4; ++i)
#pragma unroll
    for (int j = 0; j < 8; ++j) acc[i][j] = 0.f;

  const int nk = K >> 4;
  float4 aR = *(const float4*)(A + (size_t)(r0 + lrow) * K + lkq * 4);
  float4 bR0 = *(const float4*)(Bm + (size_t)kk0 * N + c0 + nq * 4);
  float4 bR1 = *(const float4*)(Bm + (size_t)(kk0 + 8) * N + c0 + nq * 4);
  As[0][lkq * 4 + 0][lrow] = aR.x; As[0][lkq * 4 + 1][lrow] = aR.y;
  As[0][lkq * 4 + 2][lrow] = aR.z; As[0][lkq * 4 + 3][lrow] = aR.w;
  *(float4*)&Bs[0][kk0][nq * 4] = bR0;
  *(float4*)&Bs[0][kk0 + 8][nq * 4] = bR1;
  __syncthreads();

  int cur = 0;
  for (int t = 0; t < nk; ++t) {
    if (t < nk - 1) {
      int kn = (t + 1) * 16;
      aR = *(const float4*)(A + (size_t)(r0 + lrow) * K + kn + lkq * 4);
      bR0 = *(const float4*)(Bm + (size_t)(kn + kk0) * N + c0 + nq * 4);
      bR1 = *(const float4*)(Bm + (size_t)(kn + kk0 + 8) * N + c0 + nq * 4);
    }
#pragma unroll
    for (int k = 0; k < 16; ++k) {
      float a[4], b[8];
      *(float4*)&a[0] = *(const float4*)&As[cur][k][tr * 4];
      *(float4*)&b[0] = *(const float4*)&Bs[cur][k][tc * 4];
      *(float4*)&b[4] = *(const float4*)&Bs[cur][k][64 + tc * 4];
#pragma unroll
      for (int i = 0; i < 4; ++i)
#pragma unroll
        for (int j = 0; j < 8; ++j) acc[i][j] = fmaf(a[i], b[j], acc[i][j]);
    }
    if (t < nk - 1) {
      int nxt = cur ^ 1;
      As[nxt][lkq * 4 + 0][lrow] = aR.x; As[nxt][lkq * 4 + 1][lrow] = aR.y;
      As[nxt][lkq * 4 + 2][lrow] = aR.z; As[nxt][lkq * 4 + 3][lrow] = aR.w;
      *(float4*)&Bs[nxt][kk0][nq * 4] = bR0;
      *(float4*)&Bs[nxt][kk0 + 8][nq * 4] = bR1;
    }
    __syncthreads();
    cur ^= 1;
  }
#pragma unroll
  for (int i = 0; i < 4; ++i) {
    int r = r0 + tr * 4 + i;
#pragma unroll
    for (int jq = 0; jq < 2; ++jq) {
      int cb = c0 + jq * 64 + tc * 4;
      *(float4*)(C + (size_t)r * N + cb) = *(float4*)&acc[i][jq * 4];
      ushort4 hb;
      hb.x = f2bf(acc[i][jq * 4 + 0]); hb.y = f2bf(acc[i][jq * 4 + 1]);
      hb.z = f2bf(acc[i][jq * 4 + 2]); hb.w = f2bf(acc[i][jq * 4 + 3]);
      *(ushort4*)(Cbf + (size_t)r * N + cb) = hb;
    }
  }
}

// ---------- bf16 MFMA GEMM, 128x128 tile, swizzled staging, 2-phase dbuf (R8) ----------
// EPI: 0 = raw f32 -> C ; 1 = gelu(x+bias) f32 -> C ; 2 = gelu(x+bias) hi/lo planes -> C2
template <int EPI>
__global__ __launch_bounds__(256) void gemm_bt(const unsigned short* __restrict__ A,
                                               const unsigned short* __restrict__ Bt,
                                               const float* __restrict__ bias,
                                               float* __restrict__ C,
                                               unsigned short* __restrict__ C2,
                                               int N, int K) {
  __shared__ __align__(16) unsigned short As[2 * 128 * 64];
  __shared__ __align__(16) unsigned short Bs[2 * 128 * 64];
  const int r0 = blockIdx.x * 128, c0 = blockIdx.y * 128;
  const int tid = threadIdx.x, lane = tid & 63, w = tid >> 6;
  const int wr = w >> 1, wc = w & 1;
  f32x4 acc[4][4];
  const f32x4 z4 = {0.f, 0.f, 0.f, 0.f};
#pragma unroll
  for (int i = 0; i < 4; ++i)
#pragma unroll
    for (int j = 0; j < 4; ++j) acc[i][j] = z4;

  const int srow = w * 32 + (lane >> 3);
  const int ksl = (lane & 7) ^ (lane >> 3);
  const unsigned short* aSrc = A + (size_t)(r0 + srow) * K + ksl * 8;
  const unsigned short* bSrc = Bt + (size_t)(c0 + srow) * K + ksl * 8;
  const int rsw = (lane & 7);
  const int nk = K >> 6;

#pragma unroll
  for (int t4 = 0; t4 < 4; ++t4) {
    gload16(aSrc + (size_t)t4 * 8 * K, (char*)As + (w * 32 + t4 * 8) * 128);
    gload16(bSrc + (size_t)t4 * 8 * K, (char*)Bs + (w * 32 + t4 * 8) * 128);
  }
  __syncthreads();

  int cur = 0;
  for (int kt = 0; kt < nk; ++kt) {
    if (kt < nk - 1) {
      const int kn = (kt + 1) * 64;
      const int off = (cur ^ 1) * 16384;
#pragma unroll
      for (int t4 = 0; t4 < 4; ++t4) {
        gload16(aSrc + kn + (size_t)t4 * 8 * K, (char*)As + off + (w * 32 + t4 * 8) * 128);
        gload16(bSrc + kn + (size_t)t4 * 8 * K, (char*)Bs + off + (w * 32 + t4 * 8) * 128);
      }
    }
    const int cbase = cur * 16384;
#pragma unroll
    for (int ks = 0; ks < 2; ++ks) {
      short8v af[4], bf[4];
      const int slot = (((ks * 4 + (lane >> 4)) ^ rsw) << 4) + cbase;
#pragma unroll
      for (int f = 0; f < 4; ++f) {
        af[f] = *(const short8v*)((const char*)As + (wr * 64 + f * 16 + (lane & 15)) * 128 + slot);
        bf[f] = *(const short8v*)((const char*)Bs + (wc * 64 + f * 16 + (lane & 15)) * 128 + slot);
      }
#pragma unroll
      for (int fi = 0; fi < 4; ++fi)
#pragma unroll
        for (int fj = 0; fj < 4; ++fj)
          acc[fi][fj] = __builtin_amdgcn_mfma_f32_16x16x32_bf16(af[fi], bf[fj], acc[fi][fj], 0, 0, 0);
    }
    __syncthreads();
    cur ^= 1;
  }
#pragma unroll
  for (int fi = 0; fi < 4; ++fi)
#pragma unroll
    for (int fj = 0; fj < 4; ++fj) {
      int col = c0 + wc * 64 + fj * 16 + (lane & 15);
      int rowb = r0 + wr * 64 + fi * 16 + (lane >> 4) * 4;
#pragma unroll
      for (int r = 0; r < 4; ++r) {
        float x = acc[fi][fj][r];
        if constexpr (EPI == 0) {
          C[(size_t)(rowb + r) * N + col] = x;
        } else if constexpr (EPI == 1) {
          C[(size_t)(rowb + r) * N + col] = gelu_f(x + bias[col]);
        } else {
          float y = gelu_f(x + bias[col]);
          unsigned short h = f2bf(y);
          unsigned short l = f2bf(y - bf2f(h));
          C2[(size_t)(rowb + r) * 2 * N + col] = h;
          C2[(size_t)(rowb + r) * 2 * N + N + col] = l;
        }
      }
    }
}

// ---------- fused S^T tiles + lane-local top-5; 2-phase dbuf (R8-verbatim) ----------
// XCD panel map: p=bid&7 (XCD), q=bid>>3; ib=p*8+(q&7); chunk=q>>3.
__global__ __launch_bounds__(512, 4) void s_topk(const unsigned short* __restrict__ Gh,
                                                 const unsigned short* __restrict__ Xh,
                                                 float* __restrict__ pv, int* __restrict__ pix) {
  __shared__ __align__(16) unsigned short As[2 * 128 * 64];   // j-tile dbuf 32 KB
  __shared__ __align__(16) unsigned short Bs[2 * 128 * 64];   // i-tile dbuf 32 KB
  const int bid = blockIdx.x;
  const int p = bid & 7, q = bid >> 3;
  const int r0 = (p * 8 + (q & 7)) * 128;
  const int chunk = q >> 3;
  const int tid = threadIdx.x, lane = tid & 63, w = tid >> 6;
  const int wr = w >> 2, wc = w & 3;
  float lv0[5], lv1[5]; int li0[5], li1[5];
#pragma unroll
  for (int q2 = 0; q2 < 5; ++q2) {
    lv0[q2] = -1e30f; li0[q2] = 0; lv1[q2] = -1e30f; li1[q2] = 0;
  }

  const int strow = tid >> 3, sslot = tid & 7;
  const int ksl = sslot ^ (strow & 7);
  const unsigned short* bSrc = Gh + (size_t)(r0 + strow) * 768 + ksl * 8;  // i rows, fixed
  char* aDst0 = (char*)As + strow * 128 + sslot * 16;
  char* bDst0 = (char*)Bs + strow * 128 + sslot * 16;
  const int rsw = lane & 7;

  // prologue: stage jt=0, k0=0 into buf0
  {
    const unsigned short* a0 = Xh + (size_t)(chunk * 1024 + strow) * 768 + ksl * 8;
    gload16(a0, aDst0);
    gload16(a0 + (size_t)64 * 768, aDst0 + 8192);
    gload16(bSrc, bDst0);
    gload16(bSrc + (size_t)64 * 768, bDst0 + 8192);
  }
  __syncthreads();

  int cur = 0;
  for (int jt = 0; jt < 8; ++jt) {
    const int j0 = chunk * 1024 + jt * 128;
    const unsigned short* aSrc = Xh + (size_t)(j0 + strow) * 768 + ksl * 8;
    f32x4 acc[4][2];
    const f32x4 z4 = {0.f, 0.f, 0.f, 0.f};
#pragma unroll
    for (int i = 0; i < 4; ++i) {
      acc[i][0] = z4; acc[i][1] = z4;
    }

    for (int t = 0; t < 12; ++t) {
      const int off = (cur ^ 1) * 16384;
      if (t < 11) {
        const int kn = (t + 1) * 64;
        gload16(aSrc + kn, aDst0 + off);
        gload16(aSrc + kn + (size_t)64 * 768, aDst0 + off + 8192);
        gload16(bSrc + kn, bDst0 + off);
        gload16(bSrc + kn + (size_t)64 * 768, bDst0 + off + 8192);
      } else if (jt < 7) {
        // prefetch next jt's k0=0 tile; its HBM latency hides under the scan below
        const unsigned short* aN = aSrc + (size_t)128 * 768;
        gload16(aN, aDst0 + off);
        gload16(aN + (size_t)64 * 768, aDst0 + off + 8192);
        gload16(bSrc, bDst0 + off);
        gload16(bSrc + (size_t)64 * 768, bDst0 + off + 8192);
      }
      const int cbase = cur * 16384;
#pragma unroll
      for (int ks = 0; ks < 2; ++ks) {
        short8v aj[4], bi[2];
        const int slot = (((ks * 4 + (lane >> 4)) ^ rsw) << 4) + cbase;
#pragma unroll
        for (int f = 0; f < 4; ++f)
          aj[f] = *(const short8v*)((const char*)As + (wr * 64 + f * 16 + (lane & 15)) * 128 + slot);
#pragma unroll
        for (int f = 0; f < 2; ++f)
          bi[f] = *(const short8v*)((const char*)Bs + (wc * 32 + f * 16 + (lane & 15)) * 128 + slot);
#pragma unroll
        for (int fi = 0; fi < 4; ++fi) {
          acc[fi][0] = __builtin_amdgcn_mfma_f32_16x16x32_bf16(aj[fi], bi[0], acc[fi][0], 0, 0, 0);
          acc[fi][1] = __builtin_amdgcn_mfma_f32_16x16x32_bf16(aj[fi], bi[1], acc[fi][1], 0, 0, 0);
        }
      }
      __syncthreads();
      cur ^= 1;
    }
    // in-register scan: lane holds 16 j-values for each of 2 i's
    const int jb = j0 + wr * 64 + (lane >> 4) * 4;
#pragma unroll
    for (int fi = 0; fi < 4; ++fi)
#pragma unroll
      for (int r = 0; r < 4; ++r) {
        int jj = jb + fi * 16 + r;
        float v0 = acc[fi][0][r];
        if (v0 > lv0[4]) insN<5>(v0, jj, lv0, li0);
        float v1 = acc[fi][1][r];
        if (v1 > lv1[4]) insN<5>(v1, jj, lv1, li1);
      }
  }
  // write per-(i, chunk, slot) top-5; slot = wr*4 + lane-group
  const int slotw = wr * 4 + (lane >> 4);
  const int ib0 = r0 + wc * 32 + (lane & 15);
  size_t base0 = (((size_t)ib0 * 8 + chunk) * 8 + slotw) * 5;
#pragma unroll
  for (int q2 = 0; q2 < 5; ++q2) { pv[base0 + q2] = lv0[q2]; pix[base0 + q2] = li0[q2]; }
  size_t base1 = (((size_t)(ib0 + 16) * 8 + chunk) * 8 + slotw) * 5;
#pragma unroll
  for (int q2 = 0; q2 < 5; ++q2) { pv[base1 + q2] = lv1[q2]; pix[base1 + q2] = li1[q2]; }
}

// merge 8 chunks x 8 slots x 5 = 320 partial entries per row -> global top-16 candidates
__global__ __launch_bounds__(256) void merge16(const float* __restrict__ pv,
                                               const int* __restrict__ pix,
                                               int* __restrict__ gidx) {
  int row = blockIdx.x * 256 + threadIdx.x;
  float lv[16]; int li[16];
#pragma unroll
  for (int q = 0; q < 16; ++q) { lv[q] = -1e30f; li[q] = 0; }
  for (int ch = 0; ch < 8; ++ch)
#pragma unroll
    for (int sl = 0; sl < 8; ++sl) {
      size_t base = (((size_t)row * 8 + ch) * 8 + sl) * 5;
#pragma unroll
      for (int q = 0; q < 5; ++q) {
        float v = pv[base + q];
        if (v > lv[15]) insN<16>(v, pix[base + q], lv, li);
      }
    }
#pragma unroll
  for (int q = 0; q < 16; ++q) gidx[row * 16 + q] = li[q];
}

// exact f32 re-evaluation of 16 candidates (incl. Ae blend), exact top-5 (ties -> lower index)
__global__ __launch_bounds__(256) void refine5(const float* __restrict__ G,
                                               const float* __restrict__ X,
                                               const float* __restrict__ Ae,
                                               const int* __restrict__ gidx,
                                               const float* __restrict__ ralpha,
                                               int* __restrict__ t5i, float* __restrict__ t5v) {
  int i = blockIdx.x * 4 + (threadIdx.x >> 6);
  int lane = threadIdx.x & 63;
  int c = lane >> 2, s = lane & 3;
  float sa = 1.f / (1.f + expf(-ralpha[0]));
  int j = gidx[i * 16 + c];
  const float* g = G + (size_t)i * 768;
  const float* x = X + (size_t)j * 768;
  float a = 0.f;
#pragma unroll 8
  for (int t = 0; t < 192; ++t) a = fmaf(g[s + 4 * t], x[s + 4 * t], a);
  a += __shfl_xor(a, 1);
  a += __shfl_xor(a, 2);
  float v = sa * Ae[(size_t)i * 8192 + j] + (1.f - sa) * fmaxf(a, 0.f);
  float vs[16]; int js[16];
#pragma unroll
  for (int q = 0; q < 16; ++q) { vs[q] = __shfl(v, q * 4); js[q] = __shfl(j, q * 4); }
  if (lane == 0) {
    unsigned used = 0;
#pragma unroll
    for (int t = 0; t < 5; ++t) {
      float bv = -1e30f; int bj = 0; int bq = 0; bool any = false;
#pragma unroll
      for (int q = 0; q < 16; ++q) {
        bool ok = ((used >> q) & 1u) == 0u;
        bool better = ok && (!any || vs[q] > bv || (vs[q] == bv && js[q] < bj));
        bv = better ? vs[q] : bv; bj = better ? js[q] : bj; bq = better ? q : bq;
        any = any || better;
      }
      used |= (1u << bq);
      t5v[(size_t)i * 5 + t] = bv;
      t5i[(size_t)i * 5 + t] = bj;
    }
  }
}

// -------- symmetrized sparse-A construction (canonical-pair dedup) --------
__global__ void edge_deg(const int* __restrict__ t5i, int* __restrict__ deg) {
  int e = blockIdx.x * 256 + threadIdx.x;
  if (e >= 40960) return;
  int i = e / 5, t = e - i * 5;
  int j = t5i[i * 5 + t];
  if (j == i) return;
  bool rev = false;
#pragma unroll
  for (int u = 0; u < 5; ++u) rev = rev || (t5i[j * 5 + u] == i);
  if (!rev || i < j) { atomicAdd(&deg[i], 1); atomicAdd(&deg[j], 1); }
}

__global__ void scan8k(const int* __restrict__ deg, int* __restrict__ off) {
  __shared__ int sums[256];
  int tid = threadIdx.x;
  int base = tid * 32;
  int s = 0;
  for (int u = 0; u < 32; ++u) s += deg[base + u];
  sums[tid] = s;
  __syncthreads();
  for (int d = 1; d < 256; d <<= 1) {
    int v = (tid >= d) ? sums[tid - d] : 0;
    __syncthreads();
    sums[tid] += v;
    __syncthreads();
  }
  int run = tid ? sums[tid - 1] : 0;
  for (int u = 0; u < 32; ++u) { off[base + u] = run; run += deg[base + u]; }
  if (tid == 255) off[8192] = run;
}

__global__ __launch_bounds__(256) void edge_fill(const int* __restrict__ t5i,
                                                 const float* __restrict__ t5v,
                                                 const float* __restrict__ G,
                                                 const float* __restrict__ X,
                                                 const float* __restrict__ Ae,
                                                 const float* __restrict__ ralpha,
                                                 const int* __restrict__ off,
                                                 int* __restrict__ cursor,
                                                 int* __restrict__ ccol, float* __restrict__ cval) {
  int e = blockIdx.x * 4 + (threadIdx.x >> 6);
  if (e >= 40960) return;
  int lane = threadIdx.x & 63;
  int i = e / 5, t = e - i * 5;
  int j = t5i[i * 5 + t];
  if (j == i) return;
  int rev = -1;
#pragma unroll
  for (int u = 0; u < 5; ++u)
    if (t5i[j * 5 + u] == i) rev = u;
  if (!(rev < 0 || i < j)) return;
  float vji;
  if (rev >= 0) {
    vji = t5v[j * 5 + rev];
  } else {
    const float* g = G + (size_t)j * 768;
    const float* x = X + (size_t)i * 768;
    float a = 0.f;
#pragma unroll
    for (int u = 0; u < 12; ++u) a = fmaf(g[lane + 64 * u], x[lane + 64 * u], a);
#pragma unroll
    for (int d = 32; d; d >>= 1) a += __shfl_xor(a, d);
    float sa = 1.f / (1.f + expf(-ralpha[0]));
    vji = sa * Ae[(size_t)j * 8192 + i] + (1.f - sa) * fmaxf(a, 0.f);
  }
  if (lane == 0) {
    float vij = t5v[i * 5 + t];
    int p0 = off[i] + atomicAdd(&cursor[i], 1);
    ccol[p0] = j; cval[p0] = vij;
    int p1 = off[j] + atomicAdd(&cursor[j], 1);
    ccol[p1] = i; cval[p1] = vji;
  }
}

// M = D^-1 * (X[i] + sum val * X[j]) ; one block per row
__global__ __launch_bounds__(256) void gather_gcn(const float* __restrict__ X,
                                                  const int* __restrict__ off,
                                                  const int* __restrict__ ccol,
                                                  const float* __restrict__ cval,
                                                  float* __restrict__ M) {
  __shared__ float red[256];
  __shared__ float sdinv;
  int i = blockIdx.x, tid = threadIdx.x;
  int s0 = off[i], cnt = off[i + 1] - s0;
  float s = 0.f;
  for (int e = tid; e < cnt; e += 256) s += cval[s0 + e];
  red[tid] = s;
  __syncthreads();
  for (int d = 128; d; d >>= 1) {
    if (tid < d) red[tid] += red[tid + d];
    __syncthreads();
  }
  if (tid == 0) sdinv = 1.f / fmaxf(1.f + red[0], 1e-8f);
  __syncthreads();
  float dinv = sdinv;
  const float* xi = X + (size_t)i * 768;
  float a0 = xi[tid], a1 = xi[tid + 256], a2 = xi[tid + 512];
  for (int e = 0; e < cnt; ++e) {
    float v = cval[s0 + e];
    const float* xr = X + (size_t)ccol[s0 + e] * 768;
    a0 = fmaf(v, xr[tid], a0);
    a1 = fmaf(v, xr[tid + 256], a1);
    a2 = fmaf(v, xr[tid + 512], a2);
  }
  float* mi = M + (size_t)i * 768;
  mi[tid] = a0 * dinv; mi[tid + 256] = a1 * dinv; mi[tid + 512] = a2 * dinv;
}

__global__ __launch_bounds__(256) void final_head(const float* __restrict__ h2,
                                                  const float* __restrict__ W3,
                                                  const float* __restrict__ b3,
                                                  float* __restrict__ out) {
  int i = blockIdx.x * 4 + (threadIdx.x >> 6);
  int lane = threadIdx.x & 63;
  const float* r = h2 + (size_t)i * 256;
  float s = r[lane] * W3[lane] + r[lane + 64] * W3[lane + 64] +
            r[lane + 128] * W3[lane + 128] + r[lane + 192] * W3[lane + 192];
#pragma unroll
  for (int d = 32; d; d >>= 1) s += __shfl_xor(s, d);
  if (lane == 0) out[i] = s + b3[0];
}

extern "C" void kernel_launch(void* const* d_in, const int* in_sizes, int n_in,
                              void* d_out, int out_size, void* d_ws, size_t ws_size,
                              hipStream_t stream) {
  const float* X   = (const float*)d_in[0];
  const float* Ae  = (const float*)d_in[1];
  const float* Wg  = (const float*)d_in[2];
  const float* ra  = (const float*)d_in[3];
  const float* Wgc = (const float*)d_in[4];
  const float* bgc = (const float*)d_in[5];
  const float* W1  = (const float*)d_in[6];
  const float* b1  = (const float*)d_in[7];
  const float* W2  = (const float*)d_in[8];
  const float* b2  = (const float*)d_in[9];
  const float* W3  = (const float*)d_in[10];
  const float* b3  = (const float*)d_in[11];
  float* out = (float*)d_out;

  char* w = (char*)d_ws;
  size_t off_ = 0;
  auto take = [&](size_t n) -> void* {
    void* p = w + off_;
    off_ += (n + 255) & ~(size_t)255;
    return p;
  };
  float* G            = (float*)take((size_t)8192 * 768 * 4);          // 25.17 MB
  unsigned short* Xh  = (unsigned short*)take((size_t)8192 * 768 * 2); // 12.58
  unsigned short* Gh  = (unsigned short*)take((size_t)8192 * 768 * 2); // 12.58
  float* pv           = (float*)take((size_t)8192 * 320 * 4);          // 10.49
  int* pix            = (int*)take((size_t)8192 * 320 * 4);            // 10.49
  int* gidx           = (int*)take((size_t)8192 * 16 * 4);
  int* t5i            = (int*)take((size_t)8192 * 5 * 4);
  float* t5v          = (float*)take((size_t)8192 * 5 * 4);
  int* deg            = (int*)take((size_t)8192 * 4);
  int* offr           = (int*)take((size_t)8193 * 4);
  int* cur            = (int*)take((size_t)8192 * 4);
  int* ccol           = (int*)take((size_t)81920 * 4);
  float* cval         = (float*)take((size_t)81920 * 4);
  unsigned short* Wc2 = (unsigned short*)take((size_t)768 * 1536 * 2); // 2.36
  unsigned short* W12 = (unsigned short*)take((size_t)512 * 1536 * 2); // 1.57
  unsigned short* W22 = (unsigned short*)take((size_t)256 * 1024 * 2); // 0.52
  // total ~76 MB

  // region reuse (stream-ordered):
  float* Mf            = (float*)Xh;            // Xh+Gh: Mf -> Hp2
  unsigned short* Hp2  = (unsigned short*)Xh;
  unsigned short* A2   = (unsigned short*)G;    // G (dead after edge_fill): A2 -> h1p2
  unsigned short* h1p2 = (unsigned short*)G;
  float* h2f = (float*)pv;                      // pv (dead after merge16): h2

  // 1. G = X @ Wg — fp32, k-ascending chain (selection-critical); bf16 copy fused
  sgemm_f32<<<dim3(128, 6), 256, 0, stream>>>(X, Wg, G, Gh, 768, 768);
  // 2. bf16 copy of X
  cvt_bf16<<<6144, 256, 0, stream>>>(X, Xh, 1572864);
  // 3. interleaved weight planes for MLP
  split_wt2<<<dim3(24, 24), 256, 0, stream>>>(Wgc, Wc2, 768, 768);
  split_wt2<<<dim3(24, 16), 256, 0, stream>>>(W1, W12, 768, 512);
  split_wt2<<<dim3(16, 8), 256, 0, stream>>>(W2, W22, 512, 256);

  // 4. fused S^T + lane-local top-5 partials (exact blend in refine5)
  s_topk<<<512, 512, 0, stream>>>(Gh, Xh, pv, pix);
  merge16<<<32, 256, 0, stream>>>(pv, pix, gidx);
  refine5<<<2048, 256, 0, stream>>>(G, X, Ae, gidx, ra, t5i, t5v);

  // 5. sparse symmetric A as CSR
  hipMemsetAsync(deg, 0, 8192 * 4, stream);
  hipMemsetAsync(cur, 0, 8192 * 4, stream);
  edge_deg<<<160, 256, 0, stream>>>(t5i, deg);
  scan8k<<<1, 256, 0, stream>>>(deg, offr);
  edge_fill<<<10240, 256, 0, stream>>>(t5i, t5v, G, X, Ae, ra, offr, cur, ccol, cval);

  // 6. M = A_norm @ X
  gather_gcn<<<8192, 256, 0, stream>>>(X, offr, ccol, cval, Mf);

  // 7. H planes = split(gelu(M @ Wgcn + bgc))
  split2<<<6144, 256, 0, stream>>>(Mf, A2, 768, 1572864);
  gemm_bt<2><<<dim3(64, 6), 256, 0, stream>>>(A2, Wc2, bgc, nullptr, Hp2, 768, 1536);

  // 8. h1 planes = split(gelu(H @ W1 + b1))
  gemm_bt<2><<<dim3(64, 4), 256, 0, stream>>>(Hp2, W12, b1, nullptr, h1p2, 512, 1536);

  // 9. h2 = gelu(h1 @ W2 + b2)
  gemm_bt<1><<<dim3(64, 2), 256, 0, stream>>>(h1p2, W22, b2, h2f, nullptr, 256, 1024);

  // 10. out = h2 @ W3 + b3
  final_head<<<2048, 256, 0, stream>>>(h2f, W3, b3, out);

  (void)in_sizes; (void)n_in; (void)out_size; (void)ws_size;
}

// Round 13
// 628.489 us; speedup vs baseline: 1.2648x; 1.0305x over previous
//
#include <hip/hip_runtime.h>
#include <math.h>

// SimpleGSLModel: B=8192, D=768, TOP_K=5
// R13 = R12 (best, 648us) + tail fusion, zero arithmetic change:
//   - cvt_bf16 fused into sgemm_f32 (blockIdx.y==0 writes f2bf of staged A rows)
//   - split2 fused into gather_gcn epilogue (writes hi/lo planes directly; Mf dropped)
//   - deg/cur zeroing folded into merge16 (memset launches dropped)
// Hot kernels (s_topk / sgemm core / gemm_bt / refine5 / sparse phase) R12-verbatim.

typedef __attribute__((ext_vector_type(8))) short short8v;
typedef __attribute__((ext_vector_type(4))) float f32x4;

__device__ __forceinline__ unsigned short f2bf(float f) {
  unsigned u = __float_as_uint(f);
  u += 0x7fffu + ((u >> 16) & 1u);   // RNE
  return (unsigned short)(u >> 16);
}
__device__ __forceinline__ float bf2f(unsigned short h) {
  return __uint_as_float(((unsigned)h) << 16);
}
__device__ __forceinline__ float gelu_f(float x) {
  return 0.5f * x * (1.f + erff(x * 0.7071067811865475f));
}
__device__ __forceinline__ void gload16(const void* g, void* l) {
  __builtin_amdgcn_global_load_lds(
      (const __attribute__((address_space(1))) unsigned int*)g,
      (__attribute__((address_space(3))) unsigned int*)l, 16, 0, 0);
}

// sorted-descending insert, static indexing, depth N
template <int N>
__device__ __forceinline__ void insN(float v, int j, float (&lv)[N], int (&li)[N]) {
#pragma unroll
  for (int p = N - 1; p >= 1; --p) {
    bool shiftv = v > lv[p - 1];
    bool here = (v > lv[p]) && !shiftv;
    float nv = shiftv ? lv[p - 1] : (here ? v : lv[p]);
    int ni = shiftv ? li[p - 1] : (here ? j : li[p]);
    lv[p] = nv; li[p] = ni;
  }
  if (v > lv[0]) { lv[0] = v; li[0] = j; }
}

// W [K x N] f32 -> transposed hi/lo interleaved bf16 [N][2K]
__global__ __launch_bounds__(256) void split_wt2(const float* __restrict__ W,
                                                 unsigned short* __restrict__ t2,
                                                 int K, int N) {
  __shared__ float tile[32][33];
  int kb = blockIdx.x * 32, nb = blockIdx.y * 32;
  int tx = threadIdx.x & 31, ty = threadIdx.x >> 5;
#pragma unroll
  for (int p = 0; p < 4; ++p)
    tile[ty + p * 8][tx] = W[(size_t)(kb + ty + p * 8) * N + nb + tx];
  __syncthreads();
#pragma unroll
  for (int p = 0; p < 4; ++p) {
    int n = ty + p * 8;
    float x = tile[tx][n];
    unsigned short h = f2bf(x);
    unsigned short l = f2bf(x - bf2f(h));
    t2[(size_t)(nb + n) * (2 * K) + kb + tx] = h;
    t2[(size_t)(nb + n) * (2 * K) + K + kb + tx] = l;
  }
}

// -------- fp32 SGEMM for G. 64x128 tile, 256 thr, 4x8/thread, reg-staged dbuf.
// b-cols {tc*4..+3} u {64+tc*4..+3} (contiguous, conflict-free). Per-element fmaf chain
// (k ascending, single acc) -> bitwise-stable output. Fused bf16 copies: Cbf = bf16(C),
// and blocks with blockIdx.y==0 also emit Xbf = bf16(A) while staging. --------
__global__ __launch_bounds__(256) void sgemm_f32(const float* __restrict__ A,
                                                 const float* __restrict__ Bm,
                                                 float* __restrict__ C,
                                                 unsigned short* __restrict__ Cbf,
                                                 unsigned short* __restrict__ Xbf,
                                                 int N, int K) {
  __shared__ float As[2][16][68];
  __shared__ float Bs[2][16][132];
  const int r0 = blockIdx.x * 64, c0 = blockIdx.y * 128;
  const int tid = threadIdx.x;
  const int tr = tid >> 4, tc = tid & 15;
  const int lrow = tid >> 2, lkq = tid & 3;
  const int kk0 = tid >> 5, nq = tid & 31;
  const bool wx = (blockIdx.y == 0);
  float acc[4][8];
#pragma unroll
  for (int i = 0; i < 4; ++i)
#pragma unroll
    for (int j = 0; j < 8; ++j) acc[i][j] = 0.f;

  const int nk = K >> 4;
  float4 aR = *(const float4*)(A + (size_t)(r0 + lrow) * K + lkq * 4);
  float4 bR0 = *(const float4*)(Bm + (size_t)kk0 * N + c0 + nq * 4);
  float4 bR1 = *(const float4*)(Bm + (size_t)(kk0 + 8) * N + c0 + nq * 4);
  if (wx) {
    ushort4 xh;
    xh.x = f2bf(aR.x); xh.y = f2bf(aR.y); xh.z = f2bf(aR.z); xh.w = f2bf(aR.w);
    *(ushort4*)(Xbf + (size_t)(r0 + lrow) * K + lkq * 4) = xh;
  }
  As[0][lkq * 4 + 0][lrow] = aR.x; As[0][lkq * 4 + 1][lrow] = aR.y;
  As[0][lkq * 4 + 2][lrow] = aR.z; As[0][lkq * 4 + 3][lrow] = aR.w;
  *(float4*)&Bs[0][kk0][nq * 4] = bR0;
  *(float4*)&Bs[0][kk0 + 8][nq * 4] = bR1;
  __syncthreads();

  int cur = 0;
  for (int t = 0; t < nk; ++t) {
    if (t < nk - 1) {
      int kn = (t + 1) * 16;
      aR = *(const float4*)(A + (size_t)(r0 + lrow) * K + kn + lkq * 4);
      bR0 = *(const float4*)(Bm + (size_t)(kn + kk0) * N + c0 + nq * 4);
      bR1 = *(const float4*)(Bm + (size_t)(kn + kk0 + 8) * N + c0 + nq * 4);
      if (wx) {
        ushort4 xh;
        xh.x = f2bf(aR.x); xh.y = f2bf(aR.y); xh.z = f2bf(aR.z); xh.w = f2bf(aR.w);
        *(ushort4*)(Xbf + (size_t)(r0 + lrow) * K + kn + lkq * 4) = xh;
      }
    }
#pragma unroll
    for (int k = 0; k < 16; ++k) {
      float a[4], b[8];
      *(float4*)&a[0] = *(const float4*)&As[cur][k][tr * 4];
      *(float4*)&b[0] = *(const float4*)&Bs[cur][k][tc * 4];
      *(float4*)&b[4] = *(const float4*)&Bs[cur][k][64 + tc * 4];
#pragma unroll
      for (int i = 0; i < 4; ++i)
#pragma unroll
        for (int j = 0; j < 8; ++j) acc[i][j] = fmaf(a[i], b[j], acc[i][j]);
    }
    if (t < nk - 1) {
      int nxt = cur ^ 1;
      As[nxt][lkq * 4 + 0][lrow] = aR.x; As[nxt][lkq * 4 + 1][lrow] = aR.y;
      As[nxt][lkq * 4 + 2][lrow] = aR.z; As[nxt][lkq * 4 + 3][lrow] = aR.w;
      *(float4*)&Bs[nxt][kk0][nq * 4] = bR0;
      *(float4*)&Bs[nxt][kk0 + 8][nq * 4] = bR1;
    }
    __syncthreads();
    cur ^= 1;
  }
#pragma unroll
  for (int i = 0; i < 4; ++i) {
    int r = r0 + tr * 4 + i;
#pragma unroll
    for (int jq = 0; jq < 2; ++jq) {
      int cb = c0 + jq * 64 + tc * 4;
      *(float4*)(C + (size_t)r * N + cb) = *(float4*)&acc[i][jq * 4];
      ushort4 hb;
      hb.x = f2bf(acc[i][jq * 4 + 0]); hb.y = f2bf(acc[i][jq * 4 + 1]);
      hb.z = f2bf(acc[i][jq * 4 + 2]); hb.w = f2bf(acc[i][jq * 4 + 3]);
      *(ushort4*)(Cbf + (size_t)r * N + cb) = hb;
    }
  }
}

// ---------- bf16 MFMA GEMM, 128x128 tile, swizzled staging, 2-phase dbuf (R8) ----------
// EPI: 0 = raw f32 -> C ; 1 = gelu(x+bias) f32 -> C ; 2 = gelu(x+bias) hi/lo planes -> C2
template <int EPI>
__global__ __launch_bounds__(256) void gemm_bt(const unsigned short* __restrict__ A,
                                               const unsigned short* __restrict__ Bt,
                                               const float* __restrict__ bias,
                                               float* __restrict__ C,
                                               unsigned short* __restrict__ C2,
                                               int N, int K) {
  __shared__ __align__(16) unsigned short As[2 * 128 * 64];
  __shared__ __align__(16) unsigned short Bs[2 * 128 * 64];
  const int r0 = blockIdx.x * 128, c0 = blockIdx.y * 128;
  const int tid = threadIdx.x, lane = tid & 63, w = tid >> 6;
  const int wr = w >> 1, wc = w & 1;
  f32x4 acc[4][4];
  const f32x4 z4 = {0.f, 0.f, 0.f, 0.f};
#pragma unroll
  for (int i = 0; i < 4; ++i)
#pragma unroll
    for (int j = 0; j < 4; ++j) acc[i][j] = z4;

  const int srow = w * 32 + (lane >> 3);
  const int ksl = (lane & 7) ^ (lane >> 3);
  const unsigned short* aSrc = A + (size_t)(r0 + srow) * K + ksl * 8;
  const unsigned short* bSrc = Bt + (size_t)(c0 + srow) * K + ksl * 8;
  const int rsw = (lane & 7);
  const int nk = K >> 6;

#pragma unroll
  for (int t4 = 0; t4 < 4; ++t4) {
    gload16(aSrc + (size_t)t4 * 8 * K, (char*)As + (w * 32 + t4 * 8) * 128);
    gload16(bSrc + (size_t)t4 * 8 * K, (char*)Bs + (w * 32 + t4 * 8) * 128);
  }
  __syncthreads();

  int cur = 0;
  for (int kt = 0; kt < nk; ++kt) {
    if (kt < nk - 1) {
      const int kn = (kt + 1) * 64;
      const int off = (cur ^ 1) * 16384;
#pragma unroll
      for (int t4 = 0; t4 < 4; ++t4) {
        gload16(aSrc + kn + (size_t)t4 * 8 * K, (char*)As + off + (w * 32 + t4 * 8) * 128);
        gload16(bSrc + kn + (size_t)t4 * 8 * K, (char*)Bs + off + (w * 32 + t4 * 8) * 128);
      }
    }
    const int cbase = cur * 16384;
#pragma unroll
    for (int ks = 0; ks < 2; ++ks) {
      short8v af[4], bf[4];
      const int slot = (((ks * 4 + (lane >> 4)) ^ rsw) << 4) + cbase;
#pragma unroll
      for (int f = 0; f < 4; ++f) {
        af[f] = *(const short8v*)((const char*)As + (wr * 64 + f * 16 + (lane & 15)) * 128 + slot);
        bf[f] = *(const short8v*)((const char*)Bs + (wc * 64 + f * 16 + (lane & 15)) * 128 + slot);
      }
#pragma unroll
      for (int fi = 0; fi < 4; ++fi)
#pragma unroll
        for (int fj = 0; fj < 4; ++fj)
          acc[fi][fj] = __builtin_amdgcn_mfma_f32_16x16x32_bf16(af[fi], bf[fj], acc[fi][fj], 0, 0, 0);
    }
    __syncthreads();
    cur ^= 1;
  }
#pragma unroll
  for (int fi = 0; fi < 4; ++fi)
#pragma unroll
    for (int fj = 0; fj < 4; ++fj) {
      int col = c0 + wc * 64 + fj * 16 + (lane & 15);
      int rowb = r0 + wr * 64 + fi * 16 + (lane >> 4) * 4;
#pragma unroll
      for (int r = 0; r < 4; ++r) {
        float x = acc[fi][fj][r];
        if constexpr (EPI == 0) {
          C[(size_t)(rowb + r) * N + col] = x;
        } else if constexpr (EPI == 1) {
          C[(size_t)(rowb + r) * N + col] = gelu_f(x + bias[col]);
        } else {
          float y = gelu_f(x + bias[col]);
          unsigned short h = f2bf(y);
          unsigned short l = f2bf(y - bf2f(h));
          C2[(size_t)(rowb + r) * 2 * N + col] = h;
          C2[(size_t)(rowb + r) * 2 * N + N + col] = l;
        }
      }
    }
}

// ---------- fused S^T tiles + lane-local top-5; 2-phase dbuf (R8-verbatim) ----------
// XCD panel map: p=bid&7 (XCD), q=bid>>3; ib=p*8+(q&7); chunk=q>>3.
__global__ __launch_bounds__(512, 4) void s_topk(const unsigned short* __restrict__ Gh,
                                                 const unsigned short* __restrict__ Xh,
                                                 float* __restrict__ pv, int* __restrict__ pix) {
  __shared__ __align__(16) unsigned short As[2 * 128 * 64];   // j-tile dbuf 32 KB
  __shared__ __align__(16) unsigned short Bs[2 * 128 * 64];   // i-tile dbuf 32 KB
  const int bid = blockIdx.x;
  const int p = bid & 7, q = bid >> 3;
  const int r0 = (p * 8 + (q & 7)) * 128;
  const int chunk = q >> 3;
  const int tid = threadIdx.x, lane = tid & 63, w = tid >> 6;
  const int wr = w >> 2, wc = w & 3;
  float lv0[5], lv1[5]; int li0[5], li1[5];
#pragma unroll
  for (int q2 = 0; q2 < 5; ++q2) {
    lv0[q2] = -1e30f; li0[q2] = 0; lv1[q2] = -1e30f; li1[q2] = 0;
  }

  const int strow = tid >> 3, sslot = tid & 7;
  const int ksl = sslot ^ (strow & 7);
  const unsigned short* bSrc = Gh + (size_t)(r0 + strow) * 768 + ksl * 8;  // i rows, fixed
  char* aDst0 = (char*)As + strow * 128 + sslot * 16;
  char* bDst0 = (char*)Bs + strow * 128 + sslot * 16;
  const int rsw = lane & 7;

  // prologue: stage jt=0, k0=0 into buf0
  {
    const unsigned short* a0 = Xh + (size_t)(chunk * 1024 + strow) * 768 + ksl * 8;
    gload16(a0, aDst0);
    gload16(a0 + (size_t)64 * 768, aDst0 + 8192);
    gload16(bSrc, bDst0);
    gload16(bSrc + (size_t)64 * 768, bDst0 + 8192);
  }
  __syncthreads();

  int cur = 0;
  for (int jt = 0; jt < 8; ++jt) {
    const int j0 = chunk * 1024 + jt * 128;
    const unsigned short* aSrc = Xh + (size_t)(j0 + strow) * 768 + ksl * 8;
    f32x4 acc[4][2];
    const f32x4 z4 = {0.f, 0.f, 0.f, 0.f};
#pragma unroll
    for (int i = 0; i < 4; ++i) {
      acc[i][0] = z4; acc[i][1] = z4;
    }

    for (int t = 0; t < 12; ++t) {
      const int off = (cur ^ 1) * 16384;
      if (t < 11) {
        const int kn = (t + 1) * 64;
        gload16(aSrc + kn, aDst0 + off);
        gload16(aSrc + kn + (size_t)64 * 768, aDst0 + off + 8192);
        gload16(bSrc + kn, bDst0 + off);
        gload16(bSrc + kn + (size_t)64 * 768, bDst0 + off + 8192);
      } else if (jt < 7) {
        // prefetch next jt's k0=0 tile; its HBM latency hides under the scan below
        const unsigned short* aN = aSrc + (size_t)128 * 768;
        gload16(aN, aDst0 + off);
        gload16(aN + (size_t)64 * 768, aDst0 + off + 8192);
        gload16(bSrc, bDst0 + off);
        gload16(bSrc + (size_t)64 * 768, bDst0 + off + 8192);
      }
      const int cbase = cur * 16384;
#pragma unroll
      for (int ks = 0; ks < 2; ++ks) {
        short8v aj[4], bi[2];
        const int slot = (((ks * 4 + (lane >> 4)) ^ rsw) << 4) + cbase;
#pragma unroll
        for (int f = 0; f < 4; ++f)
          aj[f] = *(const short8v*)((const char*)As + (wr * 64 + f * 16 + (lane & 15)) * 128 + slot);
#pragma unroll
        for (int f = 0; f < 2; ++f)
          bi[f] = *(const short8v*)((const char*)Bs + (wc * 32 + f * 16 + (lane & 15)) * 128 + slot);
#pragma unroll
        for (int fi = 0; fi < 4; ++fi) {
          acc[fi][0] = __builtin_amdgcn_mfma_f32_16x16x32_bf16(aj[fi], bi[0], acc[fi][0], 0, 0, 0);
          acc[fi][1] = __builtin_amdgcn_mfma_f32_16x16x32_bf16(aj[fi], bi[1], acc[fi][1], 0, 0, 0);
        }
      }
      __syncthreads();
      cur ^= 1;
    }
    // in-register scan: lane holds 16 j-values for each of 2 i's
    const int jb = j0 + wr * 64 + (lane >> 4) * 4;
#pragma unroll
    for (int fi = 0; fi < 4; ++fi)
#pragma unroll
      for (int r = 0; r < 4; ++r) {
        int jj = jb + fi * 16 + r;
        float v0 = acc[fi][0][r];
        if (v0 > lv0[4]) insN<5>(v0, jj, lv0, li0);
        float v1 = acc[fi][1][r];
        if (v1 > lv1[4]) insN<5>(v1, jj, lv1, li1);
      }
  }
  // write per-(i, chunk, slot) top-5; slot = wr*4 + lane-group
  const int slotw = wr * 4 + (lane >> 4);
  const int ib0 = r0 + wc * 32 + (lane & 15);
  size_t base0 = (((size_t)ib0 * 8 + chunk) * 8 + slotw) * 5;
#pragma unroll
  for (int q2 = 0; q2 < 5; ++q2) { pv[base0 + q2] = lv0[q2]; pix[base0 + q2] = li0[q2]; }
  size_t base1 = (((size_t)(ib0 + 16) * 8 + chunk) * 8 + slotw) * 5;
#pragma unroll
  for (int q2 = 0; q2 < 5; ++q2) { pv[base1 + q2] = lv1[q2]; pix[base1 + q2] = li1[q2]; }
}

// merge 8 chunks x 8 slots x 5 = 320 partial entries per row -> global top-16 candidates.
// Also zeroes deg[row] and cursor[row] for the sparse phase (next kernels).
__global__ __launch_bounds__(256) void merge16(const float* __restrict__ pv,
                                               const int* __restrict__ pix,
                                               int* __restrict__ gidx,
                                               int* __restrict__ deg,
                                               int* __restrict__ cursor) {
  int row = blockIdx.x * 256 + threadIdx.x;
  deg[row] = 0;
  cursor[row] = 0;
  float lv[16]; int li[16];
#pragma unroll
  for (int q = 0; q < 16; ++q) { lv[q] = -1e30f; li[q] = 0; }
  for (int ch = 0; ch < 8; ++ch)
#pragma unroll
    for (int sl = 0; sl < 8; ++sl) {
      size_t base = (((size_t)row * 8 + ch) * 8 + sl) * 5;
#pragma unroll
      for (int q = 0; q < 5; ++q) {
        float v = pv[base + q];
        if (v > lv[15]) insN<16>(v, pix[base + q], lv, li);
      }
    }
#pragma unroll
  for (int q = 0; q < 16; ++q) gidx[row * 16 + q] = li[q];
}

// exact f32 re-evaluation of 16 candidates (incl. Ae blend), exact top-5 (ties -> lower index)
__global__ __launch_bounds__(256) void refine5(const float* __restrict__ G,
                                               const float* __restrict__ X,
                                               const float* __restrict__ Ae,
                                               const int* __restrict__ gidx,
                                               const float* __restrict__ ralpha,
                                               int* __restrict__ t5i, float* __restrict__ t5v) {
  int i = blockIdx.x * 4 + (threadIdx.x >> 6);
  int lane = threadIdx.x & 63;
  int c = lane >> 2, s = lane & 3;
  float sa = 1.f / (1.f + expf(-ralpha[0]));
  int j = gidx[i * 16 + c];
  const float* g = G + (size_t)i * 768;
  const float* x = X + (size_t)j * 768;
  float a = 0.f;
#pragma unroll 8
  for (int t = 0; t < 192; ++t) a = fmaf(g[s + 4 * t], x[s + 4 * t], a);
  a += __shfl_xor(a, 1);
  a += __shfl_xor(a, 2);
  float v = sa * Ae[(size_t)i * 8192 + j] + (1.f - sa) * fmaxf(a, 0.f);
  float vs[16]; int js[16];
#pragma unroll
  for (int q = 0; q < 16; ++q) { vs[q] = __shfl(v, q * 4); js[q] = __shfl(j, q * 4); }
  if (lane == 0) {
    unsigned used = 0;
#pragma unroll
    for (int t = 0; t < 5; ++t) {
      float bv = -1e30f; int bj = 0; int bq = 0; bool any = false;
#pragma unroll
      for (int q = 0; q < 16; ++q) {
        bool ok = ((used >> q) & 1u) == 0u;
        bool better = ok && (!any || vs[q] > bv || (vs[q] == bv && js[q] < bj));
        bv = better ? vs[q] : bv; bj = better ? js[q] : bj; bq = better ? q : bq;
        any = any || better;
      }
      used |= (1u << bq);
      t5v[(size_t)i * 5 + t] = bv;
      t5i[(size_t)i * 5 + t] = bj;
    }
  }
}

// -------- symmetrized sparse-A construction (canonical-pair dedup) --------
__global__ void edge_deg(const int* __restrict__ t5i, int* __restrict__ deg) {
  int e = blockIdx.x * 256 + threadIdx.x;
  if (e >= 40960) return;
  int i = e / 5, t = e - i * 5;
  int j = t5i[i * 5 + t];
  if (j == i) return;
  bool rev = false;
#pragma unroll
  for (int u = 0; u < 5; ++u) rev = rev || (t5i[j * 5 + u] == i);
  if (!rev || i < j) { atomicAdd(&deg[i], 1); atomicAdd(&deg[j], 1); }
}

__global__ void scan8k(const int* __restrict__ deg, int* __restrict__ off) {
  __shared__ int sums[256];
  int tid = threadIdx.x;
  int base = tid * 32;
  int s = 0;
  for (int u = 0; u < 32; ++u) s += deg[base + u];
  sums[tid] = s;
  __syncthreads();
  for (int d = 1; d < 256; d <<= 1) {
    int v = (tid >= d) ? sums[tid - d] : 0;
    __syncthreads();
    sums[tid] += v;
    __syncthreads();
  }
  int run = tid ? sums[tid - 1] : 0;
  for (int u = 0; u < 32; ++u) { off[base + u] = run; run += deg[base + u]; }
  if (tid == 255) off[8192] = run;
}

__global__ __launch_bounds__(256) void edge_fill(const int* __restrict__ t5i,
                                                 const float* __restrict__ t5v,
                                                 const float* __restrict__ G,
                                                 const float* __restrict__ X,
                                                 const float* __restrict__ Ae,
                                                 const float* __restrict__ ralpha,
                                                 const int* __restrict__ off,
                                                 int* __restrict__ cursor,
                                                 int* __restrict__ ccol, float* __restrict__ cval) {
  int e = blockIdx.x * 4 + (threadIdx.x >> 6);
  if (e >= 40960) return;
  int lane = threadIdx.x & 63;
  int i = e / 5, t = e - i * 5;
  int j = t5i[i * 5 + t];
  if (j == i) return;
  int rev = -1;
#pragma unroll
  for (int u = 0; u < 5; ++u)
    if (t5i[j * 5 + u] == i) rev = u;
  if (!(rev < 0 || i < j)) return;
  float vji;
  if (rev >= 0) {
    vji = t5v[j * 5 + rev];
  } else {
    const float* g = G + (size_t)j * 768;
    const float* x = X + (size_t)i * 768;
    float a = 0.f;
#pragma unroll
    for (int u = 0; u < 12; ++u) a = fmaf(g[lane + 64 * u], x[lane + 64 * u], a);
#pragma unroll
    for (int d = 32; d; d >>= 1) a += __shfl_xor(a, d);
    float sa = 1.f / (1.f + expf(-ralpha[0]));
    vji = sa * Ae[(size_t)j * 8192 + i] + (1.f - sa) * fmaxf(a, 0.f);
  }
  if (lane == 0) {
    float vij = t5v[i * 5 + t];
    int p0 = off[i] + atomicAdd(&cursor[i], 1);
    ccol[p0] = j; cval[p0] = vij;
    int p1 = off[j] + atomicAdd(&cursor[j], 1);
    ccol[p1] = i; cval[p1] = vji;
  }
}

// M = D^-1 * (X[i] + sum val * X[j]); writes hi/lo bf16 planes directly (split2 fused)
__global__ __launch_bounds__(256) void gather_gcn(const float* __restrict__ X,
                                                  const int* __restrict__ off,
                                                  const int* __restrict__ ccol,
                                                  const float* __restrict__ cval,
                                                  unsigned short* __restrict__ M2) {
  __shared__ float red[256];
  __shared__ float sdinv;
  int i = blockIdx.x, tid = threadIdx.x;
  int s0 = off[i], cnt = off[i + 1] - s0;
  float s = 0.f;
  for (int e = tid; e < cnt; e += 256) s += cval[s0 + e];
  red[tid] = s;
  __syncthreads();
  for (int d = 128; d; d >>= 1) {
    if (tid < d) red[tid] += red[tid + d];
    __syncthreads();
  }
  if (tid == 0) sdinv = 1.f / fmaxf(1.f + red[0], 1e-8f);
  __syncthreads();
  float dinv = sdinv;
  const float* xi = X + (size_t)i * 768;
  float a0 = xi[tid], a1 = xi[tid + 256], a2 = xi[tid + 512];
  for (int e = 0; e < cnt; ++e) {
    float v = cval[s0 + e];
    const float* xr = X + (size_t)ccol[s0 + e] * 768;
    a0 = fmaf(v, xr[tid], a0);
    a1 = fmaf(v, xr[tid + 256], a1);
    a2 = fmaf(v, xr[tid + 512], a2);
  }
  unsigned short* m = M2 + (size_t)i * 1536;
  float y;
  unsigned short h;
  y = a0 * dinv; h = f2bf(y); m[tid] = h;        m[768 + tid] = f2bf(y - bf2f(h));
  y = a1 * dinv; h = f2bf(y); m[tid + 256] = h;  m[768 + tid + 256] = f2bf(y - bf2f(h));
  y = a2 * dinv; h = f2bf(y); m[tid + 512] = h;  m[768 + tid + 512] = f2bf(y - bf2f(h));
}

__global__ __launch_bounds__(256) void final_head(const float* __restrict__ h2,
                                                  const float* __restrict__ W3,
                                                  const float* __restrict__ b3,
                                                  float* __restrict__ out) {
  int i = blockIdx.x * 4 + (threadIdx.x >> 6);
  int lane = threadIdx.x & 63;
  const float* r = h2 + (size_t)i * 256;
  float s = r[lane] * W3[lane] + r[lane + 64] * W3[lane + 64] +
            r[lane + 128] * W3[lane + 128] + r[lane + 192] * W3[lane + 192];
#pragma unroll
  for (int d = 32; d; d >>= 1) s += __shfl_xor(s, d);
  if (lane == 0) out[i] = s + b3[0];
}

extern "C" void kernel_launch(void* const* d_in, const int* in_sizes, int n_in,
                              void* d_out, int out_size, void* d_ws, size_t ws_size,
                              hipStream_t stream) {
  const float* X   = (const float*)d_in[0];
  const float* Ae  = (const float*)d_in[1];
  const float* Wg  = (const float*)d_in[2];
  const float* ra  = (const float*)d_in[3];
  const float* Wgc = (const float*)d_in[4];
  const float* bgc = (const float*)d_in[5];
  const float* W1  = (const float*)d_in[6];
  const float* b1  = (const float*)d_in[7];
  const float* W2  = (const float*)d_in[8];
  const float* b2  = (const float*)d_in[9];
  const float* W3  = (const float*)d_in[10];
  const float* b3  = (const float*)d_in[11];
  float* out = (float*)d_out;

  char* w = (char*)d_ws;
  size_t off_ = 0;
  auto take = [&](size_t n) -> void* {
    void* p = w + off_;
    off_ += (n + 255) & ~(size_t)255;
    return p;
  };
  float* G            = (float*)take((size_t)8192 * 768 * 4);          // 25.17 MB
  unsigned short* Xh  = (unsigned short*)take((size_t)8192 * 768 * 2); // 12.58
  unsigned short* Gh  = (unsigned short*)take((size_t)8192 * 768 * 2); // 12.58
  float* pv           = (float*)take((size_t)8192 * 320 * 4);          // 10.49
  int* pix            = (int*)take((size_t)8192 * 320 * 4);            // 10.49
  int* gidx           = (int*)take((size_t)8192 * 16 * 4);
  int* t5i            = (int*)take((size_t)8192 * 5 * 4);
  float* t5v          = (float*)take((size_t)8192 * 5 * 4);
  int* deg            = (int*)take((size_t)8192 * 4);
  int* offr           = (int*)take((size_t)8193 * 4);
  int* cur            = (int*)take((size_t)8192 * 4);
  int* ccol           = (int*)take((size_t)81920 * 4);
  float* cval         = (float*)take((size_t)81920 * 4);
  unsigned short* Wc2 = (unsigned short*)take((size_t)768 * 1536 * 2); // 2.36
  unsigned short* W12 = (unsigned short*)take((size_t)512 * 1536 * 2); // 1.57
  unsigned short* W22 = (unsigned short*)take((size_t)256 * 1024 * 2); // 0.52
  // total ~76 MB

  // region reuse (stream-ordered):
  unsigned short* M2   = (unsigned short*)G;    // G (dead after edge_fill): M planes -> h1p2
  unsigned short* h1p2 = (unsigned short*)G;
  unsigned short* Hp2  = (unsigned short*)Xh;   // Xh+Gh (dead after s_topk): H planes
  float* h2f = (float*)pv;                      // pv (dead after merge16): h2

  // 1. G = X @ Wg — fp32, k-ascending chain (selection-critical); Gh + Xh fused
  sgemm_f32<<<dim3(128, 6), 256, 0, stream>>>(X, Wg, G, Gh, Xh, 768, 768);
  // 2. interleaved weight planes for MLP
  split_wt2<<<dim3(24, 24), 256, 0, stream>>>(Wgc, Wc2, 768, 768);
  split_wt2<<<dim3(24, 16), 256, 0, stream>>>(W1, W12, 768, 512);
  split_wt2<<<dim3(16, 8), 256, 0, stream>>>(W2, W22, 512, 256);

  // 3. fused S^T + lane-local top-5 partials (exact blend in refine5)
  s_topk<<<512, 512, 0, stream>>>(Gh, Xh, pv, pix);
  merge16<<<32, 256, 0, stream>>>(pv, pix, gidx, deg, cur);
  refine5<<<2048, 256, 0, stream>>>(G, X, Ae, gidx, ra, t5i, t5v);

  // 4. sparse symmetric A as CSR
  edge_deg<<<160, 256, 0, stream>>>(t5i, deg);
  scan8k<<<1, 256, 0, stream>>>(deg, offr);
  edge_fill<<<10240, 256, 0, stream>>>(t5i, t5v, G, X, Ae, ra, offr, cur, ccol, cval);

  // 5. M planes = split(D^-1 A X)   (into G region; G dead after edge_fill)
  gather_gcn<<<8192, 256, 0, stream>>>(X, offr, ccol, cval, M2);

  // 6. H planes = split(gelu(M @ Wgcn + bgc))   (into Xh region)
  gemm_bt<2><<<dim3(64, 6), 256, 0, stream>>>(M2, Wc2, bgc, nullptr, Hp2, 768, 1536);

  // 7. h1 planes = split(gelu(H @ W1 + b1))   (into G region)
  gemm_bt<2><<<dim3(64, 4), 256, 0, stream>>>(Hp2, W12, b1, nullptr, h1p2, 512, 1536);

  // 8. h2 = gelu(h1 @ W2 + b2)
  gemm_bt<1><<<dim3(64, 2), 256, 0, stream>>>(h1p2, W22, b2, h2f, nullptr, 256, 1024);

  // 9. out = h2 @ W3 + b3
  final_head<<<2048, 256, 0, stream>>>(h2f, W3, b3, out);

  (void)in_sizes; (void)n_in; (void)out_size; (void)ws_size;
}

// Round 14
// 595.146 us; speedup vs baseline: 1.3357x; 1.0560x over previous
//
#include <hip/hip_runtime.h>
#include <math.h>

// SimpleGSLModel: B=8192, D=768, TOP_K=5
// R14 = R13 (best, 628us) + tail-only changes:
//   - gather_gcn: one wave per row (no block barriers; shfl rowsum; 12-reg X row;
//     e-ascending neighbor fmaf chain preserved; fused hi/lo plane write kept)
//   - merge16: grid 32x256 -> 128x64 (4x CU coverage, same per-thread logic)
// All selection-critical kernels (sgemm_f32 / s_topk / refine5 / edge phase) R13-verbatim.

typedef __attribute__((ext_vector_type(8))) short short8v;
typedef __attribute__((ext_vector_type(4))) float f32x4;

__device__ __forceinline__ unsigned short f2bf(float f) {
  unsigned u = __float_as_uint(f);
  u += 0x7fffu + ((u >> 16) & 1u);   // RNE
  return (unsigned short)(u >> 16);
}
__device__ __forceinline__ float bf2f(unsigned short h) {
  return __uint_as_float(((unsigned)h) << 16);
}
__device__ __forceinline__ float gelu_f(float x) {
  return 0.5f * x * (1.f + erff(x * 0.7071067811865475f));
}
__device__ __forceinline__ void gload16(const void* g, void* l) {
  __builtin_amdgcn_global_load_lds(
      (const __attribute__((address_space(1))) unsigned int*)g,
      (__attribute__((address_space(3))) unsigned int*)l, 16, 0, 0);
}

// sorted-descending insert, static indexing, depth N
template <int N>
__device__ __forceinline__ void insN(float v, int j, float (&lv)[N], int (&li)[N]) {
#pragma unroll
  for (int p = N - 1; p >= 1; --p) {
    bool shiftv = v > lv[p - 1];
    bool here = (v > lv[p]) && !shiftv;
    float nv = shiftv ? lv[p - 1] : (here ? v : lv[p]);
    int ni = shiftv ? li[p - 1] : (here ? j : li[p]);
    lv[p] = nv; li[p] = ni;
  }
  if (v > lv[0]) { lv[0] = v; li[0] = j; }
}

// W [K x N] f32 -> transposed hi/lo interleaved bf16 [N][2K]
__global__ __launch_bounds__(256) void split_wt2(const float* __restrict__ W,
                                                 unsigned short* __restrict__ t2,
                                                 int K, int N) {
  __shared__ float tile[32][33];
  int kb = blockIdx.x * 32, nb = blockIdx.y * 32;
  int tx = threadIdx.x & 31, ty = threadIdx.x >> 5;
#pragma unroll
  for (int p = 0; p < 4; ++p)
    tile[ty + p * 8][tx] = W[(size_t)(kb + ty + p * 8) * N + nb + tx];
  __syncthreads();
#pragma unroll
  for (int p = 0; p < 4; ++p) {
    int n = ty + p * 8;
    float x = tile[tx][n];
    unsigned short h = f2bf(x);
    unsigned short l = f2bf(x - bf2f(h));
    t2[(size_t)(nb + n) * (2 * K) + kb + tx] = h;
    t2[(size_t)(nb + n) * (2 * K) + K + kb + tx] = l;
  }
}

// -------- fp32 SGEMM for G (R13-verbatim). 64x128, 256 thr, 4x8/thread, reg-staged dbuf.
// Contiguous b-reads; per-element fmaf chain (k ascending, single acc) -> bitwise-stable.
// Fused bf16 copies: Cbf = bf16(C); blockIdx.y==0 also emits Xbf = bf16(A). --------
__global__ __launch_bounds__(256) void sgemm_f32(const float* __restrict__ A,
                                                 const float* __restrict__ Bm,
                                                 float* __restrict__ C,
                                                 unsigned short* __restrict__ Cbf,
                                                 unsigned short* __restrict__ Xbf,
                                                 int N, int K) {
  __shared__ float As[2][16][68];
  __shared__ float Bs[2][16][132];
  const int r0 = blockIdx.x * 64, c0 = blockIdx.y * 128;
  const int tid = threadIdx.x;
  const int tr = tid >> 4, tc = tid & 15;
  const int lrow = tid >> 2, lkq = tid & 3;
  const int kk0 = tid >> 5, nq = tid & 31;
  const bool wx = (blockIdx.y == 0);
  float acc[4][8];
#pragma unroll
  for (int i = 0; i < 4; ++i)
#pragma unroll
    for (int j = 0; j < 8; ++j) acc[i][j] = 0.f;

  const int nk = K >> 4;
  float4 aR = *(const float4*)(A + (size_t)(r0 + lrow) * K + lkq * 4);
  float4 bR0 = *(const float4*)(Bm + (size_t)kk0 * N + c0 + nq * 4);
  float4 bR1 = *(const float4*)(Bm + (size_t)(kk0 + 8) * N + c0 + nq * 4);
  if (wx) {
    ushort4 xh;
    xh.x = f2bf(aR.x); xh.y = f2bf(aR.y); xh.z = f2bf(aR.z); xh.w = f2bf(aR.w);
    *(ushort4*)(Xbf + (size_t)(r0 + lrow) * K + lkq * 4) = xh;
  }
  As[0][lkq * 4 + 0][lrow] = aR.x; As[0][lkq * 4 + 1][lrow] = aR.y;
  As[0][lkq * 4 + 2][lrow] = aR.z; As[0][lkq * 4 + 3][lrow] = aR.w;
  *(float4*)&Bs[0][kk0][nq * 4] = bR0;
  *(float4*)&Bs[0][kk0 + 8][nq * 4] = bR1;
  __syncthreads();

  int cur = 0;
  for (int t = 0; t < nk; ++t) {
    if (t < nk - 1) {
      int kn = (t + 1) * 16;
      aR = *(const float4*)(A + (size_t)(r0 + lrow) * K + kn + lkq * 4);
      bR0 = *(const float4*)(Bm + (size_t)(kn + kk0) * N + c0 + nq * 4);
      bR1 = *(const float4*)(Bm + (size_t)(kn + kk0 + 8) * N + c0 + nq * 4);
      if (wx) {
        ushort4 xh;
        xh.x = f2bf(aR.x); xh.y = f2bf(aR.y); xh.z = f2bf(aR.z); xh.w = f2bf(aR.w);
        *(ushort4*)(Xbf + (size_t)(r0 + lrow) * K + kn + lkq * 4) = xh;
      }
    }
#pragma unroll
    for (int k = 0; k < 16; ++k) {
      float a[4], b[8];
      *(float4*)&a[0] = *(const float4*)&As[cur][k][tr * 4];
      *(float4*)&b[0] = *(const float4*)&Bs[cur][k][tc * 4];
      *(float4*)&b[4] = *(const float4*)&Bs[cur][k][64 + tc * 4];
#pragma unroll
      for (int i = 0; i < 4; ++i)
#pragma unroll
        for (int j = 0; j < 8; ++j) acc[i][j] = fmaf(a[i], b[j], acc[i][j]);
    }
    if (t < nk - 1) {
      int nxt = cur ^ 1;
      As[nxt][lkq * 4 + 0][lrow] = aR.x; As[nxt][lkq * 4 + 1][lrow] = aR.y;
      As[nxt][lkq * 4 + 2][lrow] = aR.z; As[nxt][lkq * 4 + 3][lrow] = aR.w;
      *(float4*)&Bs[nxt][kk0][nq * 4] = bR0;
      *(float4*)&Bs[nxt][kk0 + 8][nq * 4] = bR1;
    }
    __syncthreads();
    cur ^= 1;
  }
#pragma unroll
  for (int i = 0; i < 4; ++i) {
    int r = r0 + tr * 4 + i;
#pragma unroll
    for (int jq = 0; jq < 2; ++jq) {
      int cb = c0 + jq * 64 + tc * 4;
      *(float4*)(C + (size_t)r * N + cb) = *(float4*)&acc[i][jq * 4];
      ushort4 hb;
      hb.x = f2bf(acc[i][jq * 4 + 0]); hb.y = f2bf(acc[i][jq * 4 + 1]);
      hb.z = f2bf(acc[i][jq * 4 + 2]); hb.w = f2bf(acc[i][jq * 4 + 3]);
      *(ushort4*)(Cbf + (size_t)r * N + cb) = hb;
    }
  }
}

// ---------- bf16 MFMA GEMM, 128x128 tile, swizzled staging, 2-phase dbuf (R8) ----------
// EPI: 0 = raw f32 -> C ; 1 = gelu(x+bias) f32 -> C ; 2 = gelu(x+bias) hi/lo planes -> C2
template <int EPI>
__global__ __launch_bounds__(256) void gemm_bt(const unsigned short* __restrict__ A,
                                               const unsigned short* __restrict__ Bt,
                                               const float* __restrict__ bias,
                                               float* __restrict__ C,
                                               unsigned short* __restrict__ C2,
                                               int N, int K) {
  __shared__ __align__(16) unsigned short As[2 * 128 * 64];
  __shared__ __align__(16) unsigned short Bs[2 * 128 * 64];
  const int r0 = blockIdx.x * 128, c0 = blockIdx.y * 128;
  const int tid = threadIdx.x, lane = tid & 63, w = tid >> 6;
  const int wr = w >> 1, wc = w & 1;
  f32x4 acc[4][4];
  const f32x4 z4 = {0.f, 0.f, 0.f, 0.f};
#pragma unroll
  for (int i = 0; i < 4; ++i)
#pragma unroll
    for (int j = 0; j < 4; ++j) acc[i][j] = z4;

  const int srow = w * 32 + (lane >> 3);
  const int ksl = (lane & 7) ^ (lane >> 3);
  const unsigned short* aSrc = A + (size_t)(r0 + srow) * K + ksl * 8;
  const unsigned short* bSrc = Bt + (size_t)(c0 + srow) * K + ksl * 8;
  const int rsw = (lane & 7);
  const int nk = K >> 6;

#pragma unroll
  for (int t4 = 0; t4 < 4; ++t4) {
    gload16(aSrc + (size_t)t4 * 8 * K, (char*)As + (w * 32 + t4 * 8) * 128);
    gload16(bSrc + (size_t)t4 * 8 * K, (char*)Bs + (w * 32 + t4 * 8) * 128);
  }
  __syncthreads();

  int cur = 0;
  for (int kt = 0; kt < nk; ++kt) {
    if (kt < nk - 1) {
      const int kn = (kt + 1) * 64;
      const int off = (cur ^ 1) * 16384;
#pragma unroll
      for (int t4 = 0; t4 < 4; ++t4) {
        gload16(aSrc + kn + (size_t)t4 * 8 * K, (char*)As + off + (w * 32 + t4 * 8) * 128);
        gload16(bSrc + kn + (size_t)t4 * 8 * K, (char*)Bs + off + (w * 32 + t4 * 8) * 128);
      }
    }
    const int cbase = cur * 16384;
#pragma unroll
    for (int ks = 0; ks < 2; ++ks) {
      short8v af[4], bf[4];
      const int slot = (((ks * 4 + (lane >> 4)) ^ rsw) << 4) + cbase;
#pragma unroll
      for (int f = 0; f < 4; ++f) {
        af[f] = *(const short8v*)((const char*)As + (wr * 64 + f * 16 + (lane & 15)) * 128 + slot);
        bf[f] = *(const short8v*)((const char*)Bs + (wc * 64 + f * 16 + (lane & 15)) * 128 + slot);
      }
#pragma unroll
      for (int fi = 0; fi < 4; ++fi)
#pragma unroll
        for (int fj = 0; fj < 4; ++fj)
          acc[fi][fj] = __builtin_amdgcn_mfma_f32_16x16x32_bf16(af[fi], bf[fj], acc[fi][fj], 0, 0, 0);
    }
    __syncthreads();
    cur ^= 1;
  }
#pragma unroll
  for (int fi = 0; fi < 4; ++fi)
#pragma unroll
    for (int fj = 0; fj < 4; ++fj) {
      int col = c0 + wc * 64 + fj * 16 + (lane & 15);
      int rowb = r0 + wr * 64 + fi * 16 + (lane >> 4) * 4;
#pragma unroll
      for (int r = 0; r < 4; ++r) {
        float x = acc[fi][fj][r];
        if constexpr (EPI == 0) {
          C[(size_t)(rowb + r) * N + col] = x;
        } else if constexpr (EPI == 1) {
          C[(size_t)(rowb + r) * N + col] = gelu_f(x + bias[col]);
        } else {
          float y = gelu_f(x + bias[col]);
          unsigned short h = f2bf(y);
          unsigned short l = f2bf(y - bf2f(h));
          C2[(size_t)(rowb + r) * 2 * N + col] = h;
          C2[(size_t)(rowb + r) * 2 * N + N + col] = l;
        }
      }
    }
}

// ---------- fused S^T tiles + lane-local top-5; 2-phase dbuf (R8-verbatim) ----------
// XCD panel map: p=bid&7 (XCD), q=bid>>3; ib=p*8+(q&7); chunk=q>>3.
__global__ __launch_bounds__(512, 4) void s_topk(const unsigned short* __restrict__ Gh,
                                                 const unsigned short* __restrict__ Xh,
                                                 float* __restrict__ pv, int* __restrict__ pix) {
  __shared__ __align__(16) unsigned short As[2 * 128 * 64];   // j-tile dbuf 32 KB
  __shared__ __align__(16) unsigned short Bs[2 * 128 * 64];   // i-tile dbuf 32 KB
  const int bid = blockIdx.x;
  const int p = bid & 7, q = bid >> 3;
  const int r0 = (p * 8 + (q & 7)) * 128;
  const int chunk = q >> 3;
  const int tid = threadIdx.x, lane = tid & 63, w = tid >> 6;
  const int wr = w >> 2, wc = w & 3;
  float lv0[5], lv1[5]; int li0[5], li1[5];
#pragma unroll
  for (int q2 = 0; q2 < 5; ++q2) {
    lv0[q2] = -1e30f; li0[q2] = 0; lv1[q2] = -1e30f; li1[q2] = 0;
  }

  const int strow = tid >> 3, sslot = tid & 7;
  const int ksl = sslot ^ (strow & 7);
  const unsigned short* bSrc = Gh + (size_t)(r0 + strow) * 768 + ksl * 8;  // i rows, fixed
  char* aDst0 = (char*)As + strow * 128 + sslot * 16;
  char* bDst0 = (char*)Bs + strow * 128 + sslot * 16;
  const int rsw = lane & 7;

  // prologue: stage jt=0, k0=0 into buf0
  {
    const unsigned short* a0 = Xh + (size_t)(chunk * 1024 + strow) * 768 + ksl * 8;
    gload16(a0, aDst0);
    gload16(a0 + (size_t)64 * 768, aDst0 + 8192);
    gload16(bSrc, bDst0);
    gload16(bSrc + (size_t)64 * 768, bDst0 + 8192);
  }
  __syncthreads();

  int cur = 0;
  for (int jt = 0; jt < 8; ++jt) {
    const int j0 = chunk * 1024 + jt * 128;
    const unsigned short* aSrc = Xh + (size_t)(j0 + strow) * 768 + ksl * 8;
    f32x4 acc[4][2];
    const f32x4 z4 = {0.f, 0.f, 0.f, 0.f};
#pragma unroll
    for (int i = 0; i < 4; ++i) {
      acc[i][0] = z4; acc[i][1] = z4;
    }

    for (int t = 0; t < 12; ++t) {
      const int off = (cur ^ 1) * 16384;
      if (t < 11) {
        const int kn = (t + 1) * 64;
        gload16(aSrc + kn, aDst0 + off);
        gload16(aSrc + kn + (size_t)64 * 768, aDst0 + off + 8192);
        gload16(bSrc + kn, bDst0 + off);
        gload16(bSrc + kn + (size_t)64 * 768, bDst0 + off + 8192);
      } else if (jt < 7) {
        // prefetch next jt's k0=0 tile; its HBM latency hides under the scan below
        const unsigned short* aN = aSrc + (size_t)128 * 768;
        gload16(aN, aDst0 + off);
        gload16(aN + (size_t)64 * 768, aDst0 + off + 8192);
        gload16(bSrc, bDst0 + off);
        gload16(bSrc + (size_t)64 * 768, bDst0 + off + 8192);
      }
      const int cbase = cur * 16384;
#pragma unroll
      for (int ks = 0; ks < 2; ++ks) {
        short8v aj[4], bi[2];
        const int slot = (((ks * 4 + (lane >> 4)) ^ rsw) << 4) + cbase;
#pragma unroll
        for (int f = 0; f < 4; ++f)
          aj[f] = *(const short8v*)((const char*)As + (wr * 64 + f * 16 + (lane & 15)) * 128 + slot);
#pragma unroll
        for (int f = 0; f < 2; ++f)
          bi[f] = *(const short8v*)((const char*)Bs + (wc * 32 + f * 16 + (lane & 15)) * 128 + slot);
#pragma unroll
        for (int fi = 0; fi < 4; ++fi) {
          acc[fi][0] = __builtin_amdgcn_mfma_f32_16x16x32_bf16(aj[fi], bi[0], acc[fi][0], 0, 0, 0);
          acc[fi][1] = __builtin_amdgcn_mfma_f32_16x16x32_bf16(aj[fi], bi[1], acc[fi][1], 0, 0, 0);
        }
      }
      __syncthreads();
      cur ^= 1;
    }
    // in-register scan: lane holds 16 j-values for each of 2 i's
    const int jb = j0 + wr * 64 + (lane >> 4) * 4;
#pragma unroll
    for (int fi = 0; fi < 4; ++fi)
#pragma unroll
      for (int r = 0; r < 4; ++r) {
        int jj = jb + fi * 16 + r;
        float v0 = acc[fi][0][r];
        if (v0 > lv0[4]) insN<5>(v0, jj, lv0, li0);
        float v1 = acc[fi][1][r];
        if (v1 > lv1[4]) insN<5>(v1, jj, lv1, li1);
      }
  }
  // write per-(i, chunk, slot) top-5; slot = wr*4 + lane-group
  const int slotw = wr * 4 + (lane >> 4);
  const int ib0 = r0 + wc * 32 + (lane & 15);
  size_t base0 = (((size_t)ib0 * 8 + chunk) * 8 + slotw) * 5;
#pragma unroll
  for (int q2 = 0; q2 < 5; ++q2) { pv[base0 + q2] = lv0[q2]; pix[base0 + q2] = li0[q2]; }
  size_t base1 = (((size_t)(ib0 + 16) * 8 + chunk) * 8 + slotw) * 5;
#pragma unroll
  for (int q2 = 0; q2 < 5; ++q2) { pv[base1 + q2] = lv1[q2]; pix[base1 + q2] = li1[q2]; }
}

// merge 8 chunks x 8 slots x 5 = 320 partials per row -> top-16; zeroes deg/cursor.
// grid 128 x 64 threads (4x CU coverage vs 32x256).
__global__ __launch_bounds__(64) void merge16(const float* __restrict__ pv,
                                              const int* __restrict__ pix,
                                              int* __restrict__ gidx,
                                              int* __restrict__ deg,
                                              int* __restrict__ cursor) {
  int row = blockIdx.x * 64 + threadIdx.x;
  deg[row] = 0;
  cursor[row] = 0;
  float lv[16]; int li[16];
#pragma unroll
  for (int q = 0; q < 16; ++q) { lv[q] = -1e30f; li[q] = 0; }
  for (int ch = 0; ch < 8; ++ch)
#pragma unroll
    for (int sl = 0; sl < 8; ++sl) {
      size_t base = (((size_t)row * 8 + ch) * 8 + sl) * 5;
#pragma unroll
      for (int q = 0; q < 5; ++q) {
        float v = pv[base + q];
        if (v > lv[15]) insN<16>(v, pix[base + q], lv, li);
      }
    }
#pragma unroll
  for (int q = 0; q < 16; ++q) gidx[row * 16 + q] = li[q];
}

// exact f32 re-evaluation of 16 candidates (incl. Ae blend), exact top-5 (ties -> lower index)
__global__ __launch_bounds__(256) void refine5(const float* __restrict__ G,
                                               const float* __restrict__ X,
                                               const float* __restrict__ Ae,
                                               const int* __restrict__ gidx,
                                               const float* __restrict__ ralpha,
                                               int* __restrict__ t5i, float* __restrict__ t5v) {
  int i = blockIdx.x * 4 + (threadIdx.x >> 6);
  int lane = threadIdx.x & 63;
  int c = lane >> 2, s = lane & 3;
  float sa = 1.f / (1.f + expf(-ralpha[0]));
  int j = gidx[i * 16 + c];
  const float* g = G + (size_t)i * 768;
  const float* x = X + (size_t)j * 768;
  float a = 0.f;
#pragma unroll 8
  for (int t = 0; t < 192; ++t) a = fmaf(g[s + 4 * t], x[s + 4 * t], a);
  a += __shfl_xor(a, 1);
  a += __shfl_xor(a, 2);
  float v = sa * Ae[(size_t)i * 8192 + j] + (1.f - sa) * fmaxf(a, 0.f);
  float vs[16]; int js[16];
#pragma unroll
  for (int q = 0; q < 16; ++q) { vs[q] = __shfl(v, q * 4); js[q] = __shfl(j, q * 4); }
  if (lane == 0) {
    unsigned used = 0;
#pragma unroll
    for (int t = 0; t < 5; ++t) {
      float bv = -1e30f; int bj = 0; int bq = 0; bool any = false;
#pragma unroll
      for (int q = 0; q < 16; ++q) {
        bool ok = ((used >> q) & 1u) == 0u;
        bool better = ok && (!any || vs[q] > bv || (vs[q] == bv && js[q] < bj));
        bv = better ? vs[q] : bv; bj = better ? js[q] : bj; bq = better ? q : bq;
        any = any || better;
      }
      used |= (1u << bq);
      t5v[(size_t)i * 5 + t] = bv;
      t5i[(size_t)i * 5 + t] = bj;
    }
  }
}

// -------- symmetrized sparse-A construction (canonical-pair dedup) --------
__global__ void edge_deg(const int* __restrict__ t5i, int* __restrict__ deg) {
  int e = blockIdx.x * 256 + threadIdx.x;
  if (e >= 40960) return;
  int i = e / 5, t = e - i * 5;
  int j = t5i[i * 5 + t];
  if (j == i) return;
  bool rev = false;
#pragma unroll
  for (int u = 0; u < 5; ++u) rev = rev || (t5i[j * 5 + u] == i);
  if (!rev || i < j) { atomicAdd(&deg[i], 1); atomicAdd(&deg[j], 1); }
}

__global__ void scan8k(const int* __restrict__ deg, int* __restrict__ off) {
  __shared__ int sums[256];
  int tid = threadIdx.x;
  int base = tid * 32;
  int s = 0;
  for (int u = 0; u < 32; ++u) s += deg[base + u];
  sums[tid] = s;
  __syncthreads();
  for (int d = 1; d < 256; d <<= 1) {
    int v = (tid >= d) ? sums[tid - d] : 0;
    __syncthreads();
    sums[tid] += v;
    __syncthreads();
  }
  int run = tid ? sums[tid - 1] : 0;
  for (int u = 0; u < 32; ++u) { off[base + u] = run; run += deg[base + u]; }
  if (tid == 255) off[8192] = run;
}

__global__ __launch_bounds__(256) void edge_fill(const int* __restrict__ t5i,
                                                 const float* __restrict__ t5v,
                                                 const float* __restrict__ G,
                                                 const float* __restrict__ X,
                                                 const float* __restrict__ Ae,
                                                 const float* __restrict__ ralpha,
                                                 const int* __restrict__ off,
                                                 int* __restrict__ cursor,
                                                 int* __restrict__ ccol, float* __restrict__ cval) {
  int e = blockIdx.x * 4 + (threadIdx.x >> 6);
  if (e >= 40960) return;
  int lane = threadIdx.x & 63;
  int i = e / 5, t = e - i * 5;
  int j = t5i[i * 5 + t];
  if (j == i) return;
  int rev = -1;
#pragma unroll
  for (int u = 0; u < 5; ++u)
    if (t5i[j * 5 + u] == i) rev = u;
  if (!(rev < 0 || i < j)) return;
  float vji;
  if (rev >= 0) {
    vji = t5v[j * 5 + rev];
  } else {
    const float* g = G + (size_t)j * 768;
    const float* x = X + (size_t)i * 768;
    float a = 0.f;
#pragma unroll
    for (int u = 0; u < 12; ++u) a = fmaf(g[lane + 64 * u], x[lane + 64 * u], a);
#pragma unroll
    for (int d = 32; d; d >>= 1) a += __shfl_xor(a, d);
    float sa = 1.f / (1.f + expf(-ralpha[0]));
    vji = sa * Ae[(size_t)j * 8192 + i] + (1.f - sa) * fmaxf(a, 0.f);
  }
  if (lane == 0) {
    float vij = t5v[i * 5 + t];
    int p0 = off[i] + atomicAdd(&cursor[i], 1);
    ccol[p0] = j; cval[p0] = vij;
    int p1 = off[j] + atomicAdd(&cursor[j], 1);
    ccol[p1] = i; cval[p1] = vji;
  }
}

// M = D^-1 * (X[i] + sum val * X[j]); one WAVE per row; fused hi/lo plane write.
// Neighbor fmaf chain e-ascending (as before); rowsum via shfl tree (post-selection).
__global__ __launch_bounds__(256) void gather_gcn(const float* __restrict__ X,
                                                  const int* __restrict__ off,
                                                  const int* __restrict__ ccol,
                                                  const float* __restrict__ cval,
                                                  unsigned short* __restrict__ M2) {
  const int w = threadIdx.x >> 6, lane = threadIdx.x & 63;
  const int i = blockIdx.x * 4 + w;
  const int s0 = off[i], cnt = off[i + 1] - s0;
  float s = 0.f;
  for (int e = lane; e < cnt; e += 64) s += cval[s0 + e];
#pragma unroll
  for (int d = 32; d; d >>= 1) s += __shfl_xor(s, d);
  const float dinv = 1.f / fmaxf(1.f + s, 1e-8f);
  const float* xi = X + (size_t)i * 768;
  float a[12];
#pragma unroll
  for (int u = 0; u < 12; ++u) a[u] = xi[lane + 64 * u];
  for (int e = 0; e < cnt; ++e) {
    float v = cval[s0 + e];
    const float* xr = X + (size_t)ccol[s0 + e] * 768;
#pragma unroll
    for (int u = 0; u < 12; ++u) a[u] = fmaf(v, xr[lane + 64 * u], a[u]);
  }
  unsigned short* m = M2 + (size_t)i * 1536;
#pragma unroll
  for (int u = 0; u < 12; ++u) {
    float y = a[u] * dinv;
    unsigned short h = f2bf(y);
    m[lane + 64 * u] = h;
    m[768 + lane + 64 * u] = f2bf(y - bf2f(h));
  }
}

__global__ __launch_bounds__(256) void final_head(const float* __restrict__ h2,
                                                  const float* __restrict__ W3,
                                                  const float* __restrict__ b3,
                                                  float* __restrict__ out) {
  int i = blockIdx.x * 4 + (threadIdx.x >> 6);
  int lane = threadIdx.x & 63;
  const float* r = h2 + (size_t)i * 256;
  float s = r[lane] * W3[lane] + r[lane + 64] * W3[lane + 64] +
            r[lane + 128] * W3[lane + 128] + r[lane + 192] * W3[lane + 192];
#pragma unroll
  for (int d = 32; d; d >>= 1) s += __shfl_xor(s, d);
  if (lane == 0) out[i] = s + b3[0];
}

extern "C" void kernel_launch(void* const* d_in, const int* in_sizes, int n_in,
                              void* d_out, int out_size, void* d_ws, size_t ws_size,
                              hipStream_t stream) {
  const float* X   = (const float*)d_in[0];
  const float* Ae  = (const float*)d_in[1];
  const float* Wg  = (const float*)d_in[2];
  const float* ra  = (const float*)d_in[3];
  const float* Wgc = (const float*)d_in[4];
  const float* bgc = (const float*)d_in[5];
  const float* W1  = (const float*)d_in[6];
  const float* b1  = (const float*)d_in[7];
  const float* W2  = (const float*)d_in[8];
  const float* b2  = (const float*)d_in[9];
  const float* W3  = (const float*)d_in[10];
  const float* b3  = (const float*)d_in[11];
  float* out = (float*)d_out;

  char* w = (char*)d_ws;
  size_t off_ = 0;
  auto take = [&](size_t n) -> void* {
    void* p = w + off_;
    off_ += (n + 255) & ~(size_t)255;
    return p;
  };
  float* G            = (float*)take((size_t)8192 * 768 * 4);          // 25.17 MB
  unsigned short* Xh  = (unsigned short*)take((size_t)8192 * 768 * 2); // 12.58
  unsigned short* Gh  = (unsigned short*)take((size_t)8192 * 768 * 2); // 12.58
  float* pv           = (float*)take((size_t)8192 * 320 * 4);          // 10.49
  int* pix            = (int*)take((size_t)8192 * 320 * 4);            // 10.49
  int* gidx           = (int*)take((size_t)8192 * 16 * 4);
  int* t5i            = (int*)take((size_t)8192 * 5 * 4);
  float* t5v          = (float*)take((size_t)8192 * 5 * 4);
  int* deg            = (int*)take((size_t)8192 * 4);
  int* offr           = (int*)take((size_t)8193 * 4);
  int* cur            = (int*)take((size_t)8192 * 4);
  int* ccol           = (int*)take((size_t)81920 * 4);
  float* cval         = (float*)take((size_t)81920 * 4);
  unsigned short* Wc2 = (unsigned short*)take((size_t)768 * 1536 * 2); // 2.36
  unsigned short* W12 = (unsigned short*)take((size_t)512 * 1536 * 2); // 1.57
  unsigned short* W22 = (unsigned short*)take((size_t)256 * 1024 * 2); // 0.52
  // total ~76 MB

  // region reuse (stream-ordered):
  unsigned short* M2   = (unsigned short*)G;    // G (dead after edge_fill): M planes -> h1p2
  unsigned short* h1p2 = (unsigned short*)G;
  unsigned short* Hp2  = (unsigned short*)Xh;   // Xh+Gh (dead after s_topk): H planes
  float* h2f = (float*)pv;                      // pv (dead after merge16): h2

  // 1. G = X @ Wg — fp32, k-ascending chain (selection-critical); Gh + Xh fused
  sgemm_f32<<<dim3(128, 6), 256, 0, stream>>>(X, Wg, G, Gh, Xh, 768, 768);
  // 2. interleaved weight planes for MLP
  split_wt2<<<dim3(24, 24), 256, 0, stream>>>(Wgc, Wc2, 768, 768);
  split_wt2<<<dim3(24, 16), 256, 0, stream>>>(W1, W12, 768, 512);
  split_wt2<<<dim3(16, 8), 256, 0, stream>>>(W2, W22, 512, 256);

  // 3. fused S^T + lane-local top-5 partials (exact blend in refine5)
  s_topk<<<512, 512, 0, stream>>>(Gh, Xh, pv, pix);
  merge16<<<128, 64, 0, stream>>>(pv, pix, gidx, deg, cur);
  refine5<<<2048, 256, 0, stream>>>(G, X, Ae, gidx, ra, t5i, t5v);

  // 4. sparse symmetric A as CSR
  edge_deg<<<160, 256, 0, stream>>>(t5i, deg);
  scan8k<<<1, 256, 0, stream>>>(deg, offr);
  edge_fill<<<10240, 256, 0, stream>>>(t5i, t5v, G, X, Ae, ra, offr, cur, ccol, cval);

  // 5. M planes = split(D^-1 A X)   (into G region; G dead after edge_fill)
  gather_gcn<<<2048, 256, 0, stream>>>(X, offr, ccol, cval, M2);

  // 6. H planes = split(gelu(M @ Wgcn + bgc))   (into Xh region)
  gemm_bt<2><<<dim3(64, 6), 256, 0, stream>>>(M2, Wc2, bgc, nullptr, Hp2, 768, 1536);

  // 7. h1 planes = split(gelu(H @ W1 + b1))   (into G region)
  gemm_bt<2><<<dim3(64, 4), 256, 0, stream>>>(Hp2, W12, b1, nullptr, h1p2, 512, 1536);

  // 8. h2 = gelu(h1 @ W2 + b2)
  gemm_bt<1><<<dim3(64, 2), 256, 0, stream>>>(h1p2, W22, b2, h2f, nullptr, 256, 1024);

  // 9. out = h2 @ W3 + b3
  final_head<<<2048, 256, 0, stream>>>(h2f, W3, b3, out);

  (void)in_sizes; (void)n_in; (void)out_size; (void)ws_size;
}